// Round 2
// 464.064 us; speedup vs baseline: 1.1030x; 1.1030x over previous
//
#include <hip/hip_runtime.h>
#include <hip/hip_bf16.h>

typedef unsigned short ushort_t;
typedef __attribute__((ext_vector_type(8))) short short8;
typedef __attribute__((ext_vector_type(4))) float float4_t;
typedef __attribute__((ext_vector_type(2))) float float2_t;
typedef __attribute__((ext_vector_type(4))) unsigned int uint4_t;

#define BB 64
#define SS 1024
#define EE 512
#define DD 512
#define AA 512
#define MM (BB*SS)
#define KK 512
#define BM 128
#define BN 128
#define BK 32
#define BKP 40   // padded LDS row stride for legacy kernels
#define BK2 64   // K-step for the global_load_lds GEMMs

__device__ __forceinline__ float bf2f(ushort_t u) {
    return __uint_as_float(((unsigned int)u) << 16);
}
__device__ __forceinline__ ushort_t f2bf(float f) {
    unsigned int u = __float_as_uint(f);
    unsigned int r = u + 0x7fffu + ((u >> 16) & 1u);
    return (ushort_t)(r >> 16);
}
__device__ __forceinline__ float ldmix(int f32, const void* p, long idx) {
    return f32 ? ((const float*)p)[idx] : bf2f(((const ushort_t*)p)[idx]);
}
__device__ __forceinline__ void stmix(int f32, void* p, long idx, float v) {
    if (f32) ((float*)p)[idx] = v;
    else     ((ushort_t*)p)[idx] = f2bf(v);
}
__device__ __forceinline__ float fast_tanh(float x) {
    float e = __expf(2.f * x);
    return 1.f - 2.f / (e + 1.f);
}
// async global->LDS, 16B per lane. LDS ptr must be wave-uniform (HW adds lane*16B).
__device__ __forceinline__ void glds16(const ushort_t* g, ushort_t* l) {
    typedef __attribute__((address_space(1))) const void gas_t;
    typedef __attribute__((address_space(3))) void las_t;
    gas_t* gp = (gas_t*)g;
    las_t* lp = (las_t*)l;
    __builtin_amdgcn_global_load_lds(gp, lp, 16, 0, 0);
}

__global__ void k_detect(const ushort_t* __restrict__ enc, int* __restrict__ flag) {
    __shared__ int cnt;
    int tid = threadIdx.x;
    if (tid == 0) cnt = 0;
    __syncthreads();
    int c = 0;
    const uint4_t* p = (const uint4_t*)enc;
    for (int i = tid; i < 4096; i += 256) {
        uint4_t v = p[i];
        #pragma unroll
        for (int j = 0; j < 4; j++) {
            unsigned int u = v[j];
            if (((u >> 7) & 0xFFu) == 0xFFu || ((u >> 23) & 0xFFu) == 0xFFu) c++;
        }
    }
    atomicAdd(&cnt, c);
    __syncthreads();
    if (tid == 0) *flag = (cnt > 0) ? 1 : 0;
}

// -------- weight pre-convert: Wenc -> bf16, W1 -> bf16. grid (128, 2) --------
__global__ __launch_bounds__(256)
void k_conv_w(const void* __restrict__ Wenc, const void* __restrict__ W1,
              const int* __restrict__ flagp,
              ushort_t* __restrict__ WencB, ushort_t* __restrict__ W1B) {
    const int f32 = *flagp;
    const void* src = blockIdx.y ? W1 : Wenc;
    ushort_t* dst = blockIdx.y ? W1B : WencB;
    long e0 = ((long)blockIdx.x * 256 + threadIdx.x) * 8;
    short8 p;
    #pragma unroll
    for (int j = 0; j < 8; j++) p[j] = (short)f2bf(ldmix(f32, src, e0 + j));
    *(short8*)&dst[e0] = p;
}

// -------- enc pre-convert fp32 -> bf16 (only when input is fp32) --------
__global__ __launch_bounds__(256)
void k_conv_enc(const void* __restrict__ enc, const int* __restrict__ flagp,
                ushort_t* __restrict__ out) {
    if (*flagp == 0) return;   // already bf16; consumers read original pointer
    const float4_t* src = (const float4_t*)enc;
    size_t i0 = (size_t)blockIdx.x * 256 + threadIdx.x;
    size_t n8 = (size_t)MM * EE / 8;
    size_t stride = (size_t)gridDim.x * 256;
    for (size_t i = i0; i < n8; i += stride) {
        float4_t v0 = src[2 * i], v1 = src[2 * i + 1];
        short8 p;
        p[0] = (short)f2bf(v0[0]); p[1] = (short)f2bf(v0[1]);
        p[2] = (short)f2bf(v0[2]); p[3] = (short)f2bf(v0[3]);
        p[4] = (short)f2bf(v1[0]); p[5] = (short)f2bf(v1[1]);
        p[6] = (short)f2bf(v1[2]); p[7] = (short)f2bf(v1[3]);
        *(short8*)&out[i * 8] = p;
    }
}

// ---------------- proj_dec: wave-per-output. grid (A/4, B), 256 thr ----------------
__global__ __launch_bounds__(256)
void k_proj_dec(const void* __restrict__ dec,
                const void* __restrict__ Wdec,
                const int* __restrict__ flagp,
                float* __restrict__ proj) {
    __shared__ float x[DD];
    const int f32 = *flagp;
    const int b = blockIdx.y;
    const int tid = threadIdx.x, lane = tid & 63, wave = tid >> 6;
    x[tid]       = ldmix(f32, dec, (long)b * DD + tid);
    x[tid + 256] = ldmix(f32, dec, (long)b * DD + tid + 256);
    __syncthreads();
    const int a = blockIdx.x * 4 + wave;
    float s = 0.f;
    if (f32) {
        const float* wr = (const float*)Wdec + (size_t)a * DD + lane * 8;
        #pragma unroll
        for (int j = 0; j < 8; j++) s += wr[j] * x[lane * 8 + j];
    } else {
        const ushort_t* wr = (const ushort_t*)Wdec + (size_t)a * DD + lane * 8;
        short8 w = *(const short8*)wr;
        #pragma unroll
        for (int j = 0; j < 8; j++) s += bf2f((ushort_t)w[j]) * x[lane * 8 + j];
    }
    #pragma unroll
    for (int off = 1; off < 64; off <<= 1) s += __shfl_xor(s, off);
    if (lane == 0) proj[b * AA + a] = s;
}

// legacy register-staging (fallback path when workspace too small)
__device__ __forceinline__ void stage8(int f32, const void* g, long row, int col,
                                       ushort_t* lds) {
    if (f32) {
        const float* gf = (const float*)g + row * KK + col;
        float4_t v0 = *(const float4_t*)(gf);
        float4_t v1 = *(const float4_t*)(gf + 4);
        short8 p;
        p[0] = (short)f2bf(v0[0]); p[1] = (short)f2bf(v0[1]);
        p[2] = (short)f2bf(v0[2]); p[3] = (short)f2bf(v0[3]);
        p[4] = (short)f2bf(v1[0]); p[5] = (short)f2bf(v1[1]);
        p[6] = (short)f2bf(v1[2]); p[7] = (short)f2bf(v1[3]);
        *(short8*)lds = p;
    } else {
        const ushort_t* gb = (const ushort_t*)g + row * KK + col;
        *(short8*)lds = *(const short8*)gb;
    }
}

__global__ __launch_bounds__(256)
void k_gemm1(const void* __restrict__ Xg,
             const void* __restrict__ Bg,
             const float* __restrict__ proj_dec,
             const void* __restrict__ cov,
             const void* __restrict__ Wcov,
             const int* __restrict__ flagp,
             ushort_t* __restrict__ feats) {
    __shared__ ushort_t As[BM * BKP];
    __shared__ ushort_t Bs[BN * BKP];
    const int f32 = *flagp;
    const int tid = threadIdx.x;
    const int lane = tid & 63, wave = tid >> 6;
    const int quad = lane >> 4, l16 = lane & 15;
    const int wm = wave >> 1, wn = wave & 1;
    const int m0 = blockIdx.y * BM, n0 = blockIdx.x * BN;

    float4_t acc[4][4];
    #pragma unroll
    for (int i = 0; i < 4; i++)
        #pragma unroll
        for (int j = 0; j < 4; j++) acc[i][j] = (float4_t){0.f, 0.f, 0.f, 0.f};

    const int srow = lane >> 2;
    const int scol = (lane & 3) * 8;
    ushort_t* lA0 = &As[(wave * 32 + srow) * BKP + scol];
    ushort_t* lB0 = &Bs[(wave * 32 + srow) * BKP + scol];

    for (int kt = 0; kt < KK; kt += BK) {
        __syncthreads();
        stage8(f32, Xg, (long)(m0 + wave * 32 + srow), kt + scol, lA0);
        stage8(f32, Xg, (long)(m0 + wave * 32 + srow + 16), kt + scol, lA0 + 16 * BKP);
        stage8(f32, Bg, (long)(n0 + wave * 32 + srow), kt + scol, lB0);
        stage8(f32, Bg, (long)(n0 + wave * 32 + srow + 16), kt + scol, lB0 + 16 * BKP);
        __syncthreads();
        short8 af[4], bfr[4];
        #pragma unroll
        for (int mt = 0; mt < 4; mt++)
            af[mt] = *(const short8*)&As[(wm * 64 + mt * 16 + l16) * BKP + quad * 8];
        #pragma unroll
        for (int nt = 0; nt < 4; nt++)
            bfr[nt] = *(const short8*)&Bs[(wn * 64 + nt * 16 + l16) * BKP + quad * 8];
        #pragma unroll
        for (int mt = 0; mt < 4; mt++)
            #pragma unroll
            for (int nt = 0; nt < 4; nt++)
                acc[mt][nt] = __builtin_amdgcn_mfma_f32_16x16x32_bf16(af[mt], bfr[nt], acc[mt][nt], 0, 0, 0);
    }

    #pragma unroll
    for (int mt = 0; mt < 4; mt++) {
        #pragma unroll
        for (int r = 0; r < 4; r++) {
            int m = m0 + wm * 64 + mt * 16 + quad * 4 + r;
            int b = m >> 10;
            float covv = ldmix(f32, cov, m);
            #pragma unroll
            for (int nt = 0; nt < 4; nt++) {
                int n = n0 + wn * 64 + nt * 16 + l16;
                float v = acc[mt][nt][r] + proj_dec[b * AA + n] + covv * ldmix(f32, Wcov, n);
                feats[(size_t)m * AA + n] = f2bf(fast_tanh(v));
            }
        }
    }
}

__global__ __launch_bounds__(256)
void k_gemm2(const ushort_t* __restrict__ Xg,
             const void* __restrict__ Bg,
             const void* __restrict__ b1,
             const void* __restrict__ wattn,
             const int* __restrict__ flagp,
             float* __restrict__ scores) {
    __shared__ ushort_t As[BM * BKP];
    __shared__ ushort_t Bs[BN * BKP];
    const int f32 = *flagp;
    const int tid = threadIdx.x;
    const int lane = tid & 63, wave = tid >> 6;
    const int quad = lane >> 4, l16 = lane & 15;
    const int wm = wave >> 1, wn = wave & 1;
    const int m0 = blockIdx.y * BM, n0 = blockIdx.x * BN;

    float4_t acc[4][4];
    #pragma unroll
    for (int i = 0; i < 4; i++)
        #pragma unroll
        for (int j = 0; j < 4; j++) acc[i][j] = (float4_t){0.f, 0.f, 0.f, 0.f};

    const int srow = lane >> 2;
    const int scol = (lane & 3) * 8;
    ushort_t* lA0 = &As[(wave * 32 + srow) * BKP + scol];
    ushort_t* lB0 = &Bs[(wave * 32 + srow) * BKP + scol];

    for (int kt = 0; kt < KK; kt += BK) {
        __syncthreads();
        stage8(0,   Xg, (long)(m0 + wave * 32 + srow), kt + scol, lA0);
        stage8(0,   Xg, (long)(m0 + wave * 32 + srow + 16), kt + scol, lA0 + 16 * BKP);
        stage8(f32, Bg, (long)(n0 + wave * 32 + srow), kt + scol, lB0);
        stage8(f32, Bg, (long)(n0 + wave * 32 + srow + 16), kt + scol, lB0 + 16 * BKP);
        __syncthreads();
        short8 af[4], bfr[4];
        #pragma unroll
        for (int mt = 0; mt < 4; mt++)
            af[mt] = *(const short8*)&As[(wm * 64 + mt * 16 + l16) * BKP + quad * 8];
        #pragma unroll
        for (int nt = 0; nt < 4; nt++)
            bfr[nt] = *(const short8*)&Bs[(wn * 64 + nt * 16 + l16) * BKP + quad * 8];
        #pragma unroll
        for (int mt = 0; mt < 4; mt++)
            #pragma unroll
            for (int nt = 0; nt < 4; nt++)
                acc[mt][nt] = __builtin_amdgcn_mfma_f32_16x16x32_bf16(af[mt], bfr[nt], acc[mt][nt], 0, 0, 0);
    }

    float wv[4], bv[4];
    #pragma unroll
    for (int nt = 0; nt < 4; nt++) {
        int n = n0 + wn * 64 + nt * 16 + l16;
        wv[nt] = ldmix(f32, wattn, n);
        bv[nt] = ldmix(f32, b1, n);
    }
    #pragma unroll
    for (int mt = 0; mt < 4; mt++) {
        #pragma unroll
        for (int r = 0; r < 4; r++) {
            int m = m0 + wm * 64 + mt * 16 + quad * 4 + r;
            float s = 0.f;
            #pragma unroll
            for (int nt = 0; nt < 4; nt++) {
                int n = n0 + wn * 64 + nt * 16 + l16;
                float v = acc[mt][nt][r] + bv[nt] + bf2f(Xg[(size_t)m * AA + n]);
                s += fast_tanh(v) * wv[nt];
            }
            s += __shfl_xor(s, 1);
            s += __shfl_xor(s, 2);
            s += __shfl_xor(s, 4);
            s += __shfl_xor(s, 8);
            if (l16 == 0) atomicAdd(&scores[m], s);
        }
    }
}

// ---------------- new bf16 GEMM1: global_load_lds staging, BK=64 ----------------
// grid: 2048 blocks (1-D), bijective XCD swizzle so the 4 blocks sharing an A-tile
// land on the same XCD L2.
__global__ __launch_bounds__(256)
void k_gemm1n(const void* __restrict__ enc,
              const ushort_t* __restrict__ enc_bf,
              const ushort_t* __restrict__ Wenc_bf,
              const float* __restrict__ proj_dec,
              const void* __restrict__ cov,
              const void* __restrict__ Wcov,
              const int* __restrict__ flagp,
              ushort_t* __restrict__ feats) {
    __shared__ ushort_t As[BM * BK2];   // 16 KB, linear (global_load_lds needs contiguous)
    __shared__ ushort_t Bs[BN * BK2];   // 16 KB
    const int f32 = *flagp;
    const ushort_t* Abf = f32 ? enc_bf : (const ushort_t*)enc;

    const int lid = ((blockIdx.x & 7) << 8) | (blockIdx.x >> 3);  // bijective: 2048 = 8*256
    const int m0 = (lid >> 2) * BM;
    const int n0 = (lid & 3) * BN;

    const int tid = threadIdx.x;
    const int lane = tid & 63, wave = tid >> 6;
    const int quad = lane >> 4, l16 = lane & 15;
    const int wm = wave >> 1, wn = wave & 1;
    const int l8r = lane >> 3;          // row within 8-row chunk
    const int l8c = (lane & 7) * 8;     // col (bf16 units) within 64-wide row

    float4_t acc[4][4];
    #pragma unroll
    for (int i = 0; i < 4; i++)
        #pragma unroll
        for (int j = 0; j < 4; j++) acc[i][j] = (float4_t){0.f, 0.f, 0.f, 0.f};

    for (int kt = 0; kt < KK; kt += BK2) {
        __syncthreads();   // previous iter's ds_reads done before overwrite
        #pragma unroll
        for (int i = 0; i < 4; i++) {
            int ch = i * 4 + wave;     // 16 chunks of 8 rows x 64 cols (1 KB each)
            glds16(Abf     + (((size_t)(m0 + ch * 8 + l8r)) << 9) + kt + l8c, &As[ch * 512]);
            glds16(Wenc_bf + (((size_t)(n0 + ch * 8 + l8r)) << 9) + kt + l8c, &Bs[ch * 512]);
        }
        __syncthreads();   // compiler inserts vmcnt(0) drain before barrier
        #pragma unroll
        for (int kk = 0; kk < 2; kk++) {
            short8 af[4], bfv[4];
            #pragma unroll
            for (int mt = 0; mt < 4; mt++)
                af[mt] = *(const short8*)&As[(wm * 64 + mt * 16 + l16) * BK2 + kk * 32 + quad * 8];
            #pragma unroll
            for (int nt = 0; nt < 4; nt++)
                bfv[nt] = *(const short8*)&Bs[(wn * 64 + nt * 16 + l16) * BK2 + kk * 32 + quad * 8];
            #pragma unroll
            for (int mt = 0; mt < 4; mt++)
                #pragma unroll
                for (int nt = 0; nt < 4; nt++)
                    acc[mt][nt] = __builtin_amdgcn_mfma_f32_16x16x32_bf16(af[mt], bfv[nt], acc[mt][nt], 0, 0, 0);
        }
    }

    #pragma unroll
    for (int mt = 0; mt < 4; mt++) {
        #pragma unroll
        for (int r = 0; r < 4; r++) {
            int m = m0 + wm * 64 + mt * 16 + quad * 4 + r;
            int b = m >> 10;
            float covv = ldmix(f32, cov, m);
            #pragma unroll
            for (int nt = 0; nt < 4; nt++) {
                int n = n0 + wn * 64 + nt * 16 + l16;
                float v = acc[mt][nt][r] + proj_dec[b * AA + n] + covv * ldmix(f32, Wcov, n);
                feats[(size_t)m * AA + n] = f2bf(fast_tanh(v));
            }
        }
    }
}

// ---------------- new bf16 GEMM2: feats @ W1^T, same structure ----------------
__global__ __launch_bounds__(256)
void k_gemm2n(const ushort_t* __restrict__ Xg,      // feats (bf16)
              const ushort_t* __restrict__ W1_bf,
              const void* __restrict__ b1,
              const void* __restrict__ wattn,
              const int* __restrict__ flagp,
              float* __restrict__ scores) {
    __shared__ ushort_t As[BM * BK2];
    __shared__ ushort_t Bs[BN * BK2];
    const int f32 = *flagp;

    const int lid = ((blockIdx.x & 7) << 8) | (blockIdx.x >> 3);
    const int m0 = (lid >> 2) * BM;
    const int n0 = (lid & 3) * BN;

    const int tid = threadIdx.x;
    const int lane = tid & 63, wave = tid >> 6;
    const int quad = lane >> 4, l16 = lane & 15;
    const int wm = wave >> 1, wn = wave & 1;
    const int l8r = lane >> 3;
    const int l8c = (lane & 7) * 8;

    float4_t acc[4][4];
    #pragma unroll
    for (int i = 0; i < 4; i++)
        #pragma unroll
        for (int j = 0; j < 4; j++) acc[i][j] = (float4_t){0.f, 0.f, 0.f, 0.f};

    for (int kt = 0; kt < KK; kt += BK2) {
        __syncthreads();
        #pragma unroll
        for (int i = 0; i < 4; i++) {
            int ch = i * 4 + wave;
            glds16(Xg    + (((size_t)(m0 + ch * 8 + l8r)) << 9) + kt + l8c, &As[ch * 512]);
            glds16(W1_bf + (((size_t)(n0 + ch * 8 + l8r)) << 9) + kt + l8c, &Bs[ch * 512]);
        }
        __syncthreads();
        #pragma unroll
        for (int kk = 0; kk < 2; kk++) {
            short8 af[4], bfv[4];
            #pragma unroll
            for (int mt = 0; mt < 4; mt++)
                af[mt] = *(const short8*)&As[(wm * 64 + mt * 16 + l16) * BK2 + kk * 32 + quad * 8];
            #pragma unroll
            for (int nt = 0; nt < 4; nt++)
                bfv[nt] = *(const short8*)&Bs[(wn * 64 + nt * 16 + l16) * BK2 + kk * 32 + quad * 8];
            #pragma unroll
            for (int mt = 0; mt < 4; mt++)
                #pragma unroll
                for (int nt = 0; nt < 4; nt++)
                    acc[mt][nt] = __builtin_amdgcn_mfma_f32_16x16x32_bf16(af[mt], bfv[nt], acc[mt][nt], 0, 0, 0);
        }
    }

    float wv[4], bv[4];
    #pragma unroll
    for (int nt = 0; nt < 4; nt++) {
        int n = n0 + wn * 64 + nt * 16 + l16;
        wv[nt] = ldmix(f32, wattn, n);
        bv[nt] = ldmix(f32, b1, n);
    }
    #pragma unroll
    for (int mt = 0; mt < 4; mt++) {
        #pragma unroll
        for (int r = 0; r < 4; r++) {
            int m = m0 + wm * 64 + mt * 16 + quad * 4 + r;
            float s = 0.f;
            #pragma unroll
            for (int nt = 0; nt < 4; nt++) {
                int n = n0 + wn * 64 + nt * 16 + l16;
                float v = acc[mt][nt][r] + bv[nt] + bf2f(Xg[(size_t)m * AA + n]);
                s += fast_tanh(v) * wv[nt];
            }
            s += __shfl_xor(s, 1);
            s += __shfl_xor(s, 2);
            s += __shfl_xor(s, 4);
            s += __shfl_xor(s, 8);
            if (l16 == 0) atomicAdd(&scores[m], s);
        }
    }
}

__global__ void k_softmax(const float* __restrict__ scores,
                          const int* __restrict__ mask,
                          const void* __restrict__ cov,
                          const int* __restrict__ flagp,
                          float* __restrict__ attnw,
                          void* __restrict__ dout) {
    __shared__ float red[4];
    const int f32 = *flagp;
    int b = blockIdx.x, tid = threadIdx.x;
    float v[4];
    #pragma unroll
    for (int i = 0; i < 4; i++) {
        int s = tid + i * 256;
        float sc = scores[b * SS + s];
        if (mask[b * SS + s] == 0) sc = -1e9f;
        v[i] = sc;
    }
    float mx = fmaxf(fmaxf(v[0], v[1]), fmaxf(v[2], v[3]));
    #pragma unroll
    for (int off = 1; off < 64; off <<= 1) mx = fmaxf(mx, __shfl_xor(mx, off));
    if ((tid & 63) == 0) red[tid >> 6] = mx;
    __syncthreads();
    mx = fmaxf(fmaxf(red[0], red[1]), fmaxf(red[2], red[3]));
    __syncthreads();
    float e[4], sum = 0.f;
    #pragma unroll
    for (int i = 0; i < 4; i++) { e[i] = expf(v[i] - mx); sum += e[i]; }
    #pragma unroll
    for (int off = 1; off < 64; off <<= 1) sum += __shfl_xor(sum, off);
    if ((tid & 63) == 0) red[tid >> 6] = sum;
    __syncthreads();
    sum = red[0] + red[1] + red[2] + red[3];
    float inv = 1.0f / sum;
    #pragma unroll
    for (int i = 0; i < 4; i++) {
        int s = tid + i * 256;
        float w = e[i] * inv;
        attnw[b * SS + s] = w;
        stmix(f32, dout, 32768L + (long)b * SS + s, w);
        stmix(f32, dout, 98304L + (long)b * SS + s, ldmix(f32, cov, (long)b * SS + s) + w);
    }
}

__global__ void k_context(const void* __restrict__ enc,
                          const ushort_t* __restrict__ enc_bf,
                          const int pre,
                          const float* __restrict__ attnw,
                          const int* __restrict__ flagp,
                          float* __restrict__ ctx) {
    int f32 = *flagp;
    const void* e = enc;
    if (pre && f32) { e = enc_bf; f32 = 0; }   // use pre-converted bf16 copy
    int b = blockIdx.x, sc = blockIdx.y;
    int tid = threadIdx.x;
    float a0 = 0.f, a1 = 0.f;
    const float* wrow = attnw + b * SS + sc * 128;
    if (f32) {
        const float* base = (const float*)e + ((size_t)b * SS + sc * 128) * EE;
        for (int s = 0; s < 128; s++) {
            float w = wrow[s];
            float2_t u = *(const float2_t*)(base + (size_t)s * EE + 2 * tid);
            a0 += w * u[0];
            a1 += w * u[1];
        }
    } else {
        const unsigned int* base = (const unsigned int*)e + ((size_t)b * SS + sc * 128) * (EE / 2);
        for (int s = 0; s < 128; s++) {
            float w = wrow[s];
            unsigned int u = base[(size_t)s * (EE / 2) + tid];
            a0 += w * bf2f((ushort_t)(u & 0xffff));
            a1 += w * bf2f((ushort_t)(u >> 16));
        }
    }
    atomicAdd(&ctx[b * EE + 2 * tid], a0);
    atomicAdd(&ctx[b * EE + 2 * tid + 1], a1);
}

// ---------------- gate: wave-per-output. grid (A/4, B), 256 thr ----------------
__global__ __launch_bounds__(256)
void k_gate(const float* __restrict__ ctx,
            const void* __restrict__ dec,
            const void* __restrict__ Wg,
            const void* __restrict__ bg,
            const int* __restrict__ flagp,
            void* __restrict__ dout) {
    __shared__ float gin[EE + DD];
    const int f32 = *flagp;
    const int b = blockIdx.y;
    const int tid = threadIdx.x, lane = tid & 63, wave = tid >> 6;
    gin[2 * tid]     = ctx[b * EE + 2 * tid];
    gin[2 * tid + 1] = ctx[b * EE + 2 * tid + 1];
    gin[EE + tid]       = ldmix(f32, dec, (long)b * DD + tid);
    gin[EE + tid + 256] = ldmix(f32, dec, (long)b * DD + tid + 256);
    __syncthreads();
    const int a = blockIdx.x * 4 + wave;
    float s = 0.f;
    if (f32) {
        const float* wr = (const float*)Wg + (size_t)a * (EE + DD) + lane * 16;
        #pragma unroll
        for (int j = 0; j < 16; j++) s += wr[j] * gin[lane * 16 + j];
    } else {
        const ushort_t* wr = (const ushort_t*)Wg + (size_t)a * (EE + DD) + lane * 16;
        short8 w0 = *(const short8*)wr;
        short8 w1 = *(const short8*)(wr + 8);
        #pragma unroll
        for (int j = 0; j < 8; j++) {
            s += bf2f((ushort_t)w0[j]) * gin[lane * 16 + j];
            s += bf2f((ushort_t)w1[j]) * gin[lane * 16 + 8 + j];
        }
    }
    #pragma unroll
    for (int off = 1; off < 64; off <<= 1) s += __shfl_xor(s, off);
    if (lane == 0) {
        float acc = s + ldmix(f32, bg, a);
        float g = 1.f / (1.f + __expf(-acc));
        stmix(f32, dout, (long)b * AA + a, g * ctx[b * EE + a]);
    }
}

extern "C" void kernel_launch(void* const* d_in, const int* in_sizes, int n_in,
                              void* d_out, int out_size, void* d_ws, size_t ws_size,
                              hipStream_t stream) {
    const void* enc   = d_in[0];
    const void* dec   = d_in[1];
    const int*  mask  = (const int*)d_in[2];
    const void* cov   = d_in[3];
    const void* Wenc  = d_in[4];
    const void* Wdec  = d_in[5];
    const void* wattn = d_in[6];
    const void* Wl1   = d_in[7];
    const void* b1    = d_in[8];
    const void* Wcov  = d_in[9];
    const void* Wg    = d_in[10];
    const void* bg    = d_in[11];

    // Layout keeps feats at the previously-verified offset; extra buffers are
    // appended after it and gated on ws_size so the minimum footprint equals
    // the previously-passing kernel's (68157440 B).
    char* ws = (char*)d_ws;
    float*    scores = (float*)ws;                  // 262144 B
    float*    ctx    = (float*)(ws + 262144);       // 131072 B
    float*    attnw  = (float*)(ws + 393216);       // 262144 B
    float*    projd  = (float*)(ws + 655360);       // 131072 B
    int*      flag   = (int*)(ws + 786432);         // 4 B
    ushort_t* feats  = (ushort_t*)(ws + 1048576);   // 67108864 B -> ends 68157440
    ushort_t* W1b    = (ushort_t*)(ws + 68157440);  // 524288 B   -> ends 68681728
    ushort_t* Wencb  = (ushort_t*)(ws + 68681728);  // 524288 B   -> ends 69206016
    ushort_t* encb   = (ushort_t*)(ws + 69206016);  // 67108864 B -> ends 136314880
    const int pre2 = (ws_size >= 69206016UL)  ? 1 : 0;  // bf16 weight copies fit
    const int pre1 = (ws_size >= 136314880UL) ? 1 : 0;  // bf16 enc copy also fits

    hipMemsetAsync(ws, 0, 393216, stream);
    k_detect<<<1, 256, 0, stream>>>((const ushort_t*)enc, flag);
    if (pre2)
        k_conv_w<<<dim3(128, 2), 256, 0, stream>>>(Wenc, Wl1, flag, Wencb, W1b);
    if (pre1)
        k_conv_enc<<<4096, 256, 0, stream>>>(enc, flag, encb);
    k_proj_dec<<<dim3(AA / 4, BB), 256, 0, stream>>>(dec, Wdec, flag, projd);
    if (pre1)
        k_gemm1n<<<2048, 256, 0, stream>>>(enc, encb, Wencb, projd, cov, Wcov, flag, feats);
    else
        k_gemm1<<<dim3(AA / BN, MM / BM), 256, 0, stream>>>(enc, Wenc, projd, cov, Wcov, flag, feats);
    if (pre2)
        k_gemm2n<<<2048, 256, 0, stream>>>(feats, W1b, b1, wattn, flag, scores);
    else
        k_gemm2<<<dim3(AA / BN, MM / BM), 256, 0, stream>>>(feats, Wl1, b1, wattn, flag, scores);
    k_softmax<<<BB, 256, 0, stream>>>(scores, mask, cov, flag, attnw, d_out);
    k_context<<<dim3(BB, 8), 256, 0, stream>>>(enc, encb, pre1, attnw, flag, ctx);
    k_gate<<<dim3(AA / 4, BB), 256, 0, stream>>>(ctx, dec, Wg, bg, flag, d_out);
}

// Round 3
// 434.837 us; speedup vs baseline: 1.1771x; 1.0672x over previous
//
#include <hip/hip_runtime.h>
#include <hip/hip_bf16.h>

typedef unsigned short ushort_t;
typedef __attribute__((ext_vector_type(8))) short short8;
typedef __attribute__((ext_vector_type(4))) float float4_t;
typedef __attribute__((ext_vector_type(2))) float float2_t;
typedef __attribute__((ext_vector_type(4))) unsigned int uint4_t;

#define BB 64
#define SS 1024
#define EE 512
#define DD 512
#define AA 512
#define MM (BB*SS)
#define KK 512
#define BM 128
#define BN 128
#define BK 32
#define BKP 40   // padded LDS row stride for legacy kernels
#define BK2 64   // K-step for the global_load_lds GEMMs
#define NT (KK/BK2)

__device__ __forceinline__ float bf2f(ushort_t u) {
    return __uint_as_float(((unsigned int)u) << 16);
}
__device__ __forceinline__ ushort_t f2bf(float f) {
    unsigned int u = __float_as_uint(f);
    unsigned int r = u + 0x7fffu + ((u >> 16) & 1u);
    return (ushort_t)(r >> 16);
}
__device__ __forceinline__ float ldmix(int f32, const void* p, long idx) {
    return f32 ? ((const float*)p)[idx] : bf2f(((const ushort_t*)p)[idx]);
}
__device__ __forceinline__ void stmix(int f32, void* p, long idx, float v) {
    if (f32) ((float*)p)[idx] = v;
    else     ((ushort_t*)p)[idx] = f2bf(v);
}
__device__ __forceinline__ float fast_tanh(float x) {
    float e = __expf(2.f * x);
    return 1.f - 2.f / (e + 1.f);
}
// async global->LDS, 16B per lane. LDS ptr must be wave-uniform (HW adds lane*16B).
__device__ __forceinline__ void glds16(const ushort_t* g, ushort_t* l) {
    typedef __attribute__((address_space(1))) const void gas_t;
    typedef __attribute__((address_space(3))) void las_t;
    gas_t* gp = (gas_t*)g;
    las_t* lp = (las_t*)l;
    __builtin_amdgcn_global_load_lds(gp, lp, 16, 0, 0);
}

__global__ void k_detect(const ushort_t* __restrict__ enc, int* __restrict__ flag) {
    __shared__ int cnt;
    int tid = threadIdx.x;
    if (tid == 0) cnt = 0;
    __syncthreads();
    int c = 0;
    const uint4_t* p = (const uint4_t*)enc;
    for (int i = tid; i < 4096; i += 256) {
        uint4_t v = p[i];
        #pragma unroll
        for (int j = 0; j < 4; j++) {
            unsigned int u = v[j];
            if (((u >> 7) & 0xFFu) == 0xFFu || ((u >> 23) & 0xFFu) == 0xFFu) c++;
        }
    }
    atomicAdd(&cnt, c);
    __syncthreads();
    if (tid == 0) *flag = (cnt > 0) ? 1 : 0;
}

// -------- weight pre-convert: Wenc -> bf16, W1 -> bf16. grid (128, 2) --------
__global__ __launch_bounds__(256)
void k_conv_w(const void* __restrict__ Wenc, const void* __restrict__ W1,
              const int* __restrict__ flagp,
              ushort_t* __restrict__ WencB, ushort_t* __restrict__ W1B) {
    const int f32 = *flagp;
    const void* src = blockIdx.y ? W1 : Wenc;
    ushort_t* dst = blockIdx.y ? W1B : WencB;
    long e0 = ((long)blockIdx.x * 256 + threadIdx.x) * 8;
    short8 p;
    #pragma unroll
    for (int j = 0; j < 8; j++) p[j] = (short)f2bf(ldmix(f32, src, e0 + j));
    *(short8*)&dst[e0] = p;
}

// -------- enc pre-convert fp32 -> bf16 (only when input is fp32) --------
__global__ __launch_bounds__(256)
void k_conv_enc(const void* __restrict__ enc, const int* __restrict__ flagp,
                ushort_t* __restrict__ out) {
    if (*flagp == 0) return;   // already bf16; consumers read original pointer
    const float4_t* src = (const float4_t*)enc;
    size_t i0 = (size_t)blockIdx.x * 256 + threadIdx.x;
    size_t n8 = (size_t)MM * EE / 8;
    size_t stride = (size_t)gridDim.x * 256;
    for (size_t i = i0; i < n8; i += stride) {
        float4_t v0 = src[2 * i], v1 = src[2 * i + 1];
        short8 p;
        p[0] = (short)f2bf(v0[0]); p[1] = (short)f2bf(v0[1]);
        p[2] = (short)f2bf(v0[2]); p[3] = (short)f2bf(v0[3]);
        p[4] = (short)f2bf(v1[0]); p[5] = (short)f2bf(v1[1]);
        p[6] = (short)f2bf(v1[2]); p[7] = (short)f2bf(v1[3]);
        *(short8*)&out[i * 8] = p;
    }
}

// ---------------- proj_dec: wave-per-output. grid (A/4, B), 256 thr ----------------
__global__ __launch_bounds__(256)
void k_proj_dec(const void* __restrict__ dec,
                const void* __restrict__ Wdec,
                const int* __restrict__ flagp,
                float* __restrict__ proj) {
    __shared__ float x[DD];
    const int f32 = *flagp;
    const int b = blockIdx.y;
    const int tid = threadIdx.x, lane = tid & 63, wave = tid >> 6;
    x[tid]       = ldmix(f32, dec, (long)b * DD + tid);
    x[tid + 256] = ldmix(f32, dec, (long)b * DD + tid + 256);
    __syncthreads();
    const int a = blockIdx.x * 4 + wave;
    float s = 0.f;
    if (f32) {
        const float* wr = (const float*)Wdec + (size_t)a * DD + lane * 8;
        #pragma unroll
        for (int j = 0; j < 8; j++) s += wr[j] * x[lane * 8 + j];
    } else {
        const ushort_t* wr = (const ushort_t*)Wdec + (size_t)a * DD + lane * 8;
        short8 w = *(const short8*)wr;
        #pragma unroll
        for (int j = 0; j < 8; j++) s += bf2f((ushort_t)w[j]) * x[lane * 8 + j];
    }
    #pragma unroll
    for (int off = 1; off < 64; off <<= 1) s += __shfl_xor(s, off);
    if (lane == 0) proj[b * AA + a] = s;
}

// legacy register-staging (fallback path when workspace too small)
__device__ __forceinline__ void stage8(int f32, const void* g, long row, int col,
                                       ushort_t* lds) {
    if (f32) {
        const float* gf = (const float*)g + row * KK + col;
        float4_t v0 = *(const float4_t*)(gf);
        float4_t v1 = *(const float4_t*)(gf + 4);
        short8 p;
        p[0] = (short)f2bf(v0[0]); p[1] = (short)f2bf(v0[1]);
        p[2] = (short)f2bf(v0[2]); p[3] = (short)f2bf(v0[3]);
        p[4] = (short)f2bf(v1[0]); p[5] = (short)f2bf(v1[1]);
        p[6] = (short)f2bf(v1[2]); p[7] = (short)f2bf(v1[3]);
        *(short8*)lds = p;
    } else {
        const ushort_t* gb = (const ushort_t*)g + row * KK + col;
        *(short8*)lds = *(const short8*)gb;
    }
}

__global__ __launch_bounds__(256)
void k_gemm1(const void* __restrict__ Xg,
             const void* __restrict__ Bg,
             const float* __restrict__ proj_dec,
             const void* __restrict__ cov,
             const void* __restrict__ Wcov,
             const int* __restrict__ flagp,
             ushort_t* __restrict__ feats) {
    __shared__ ushort_t As[BM * BKP];
    __shared__ ushort_t Bs[BN * BKP];
    const int f32 = *flagp;
    const int tid = threadIdx.x;
    const int lane = tid & 63, wave = tid >> 6;
    const int quad = lane >> 4, l16 = lane & 15;
    const int wm = wave >> 1, wn = wave & 1;
    const int m0 = blockIdx.y * BM, n0 = blockIdx.x * BN;

    float4_t acc[4][4];
    #pragma unroll
    for (int i = 0; i < 4; i++)
        #pragma unroll
        for (int j = 0; j < 4; j++) acc[i][j] = (float4_t){0.f, 0.f, 0.f, 0.f};

    const int srow = lane >> 2;
    const int scol = (lane & 3) * 8;
    ushort_t* lA0 = &As[(wave * 32 + srow) * BKP + scol];
    ushort_t* lB0 = &Bs[(wave * 32 + srow) * BKP + scol];

    for (int kt = 0; kt < KK; kt += BK) {
        __syncthreads();
        stage8(f32, Xg, (long)(m0 + wave * 32 + srow), kt + scol, lA0);
        stage8(f32, Xg, (long)(m0 + wave * 32 + srow + 16), kt + scol, lA0 + 16 * BKP);
        stage8(f32, Bg, (long)(n0 + wave * 32 + srow), kt + scol, lB0);
        stage8(f32, Bg, (long)(n0 + wave * 32 + srow + 16), kt + scol, lB0 + 16 * BKP);
        __syncthreads();
        short8 af[4], bfr[4];
        #pragma unroll
        for (int mt = 0; mt < 4; mt++)
            af[mt] = *(const short8*)&As[(wm * 64 + mt * 16 + l16) * BKP + quad * 8];
        #pragma unroll
        for (int nt = 0; nt < 4; nt++)
            bfr[nt] = *(const short8*)&Bs[(wn * 64 + nt * 16 + l16) * BKP + quad * 8];
        #pragma unroll
        for (int mt = 0; mt < 4; mt++)
            #pragma unroll
            for (int nt = 0; nt < 4; nt++)
                acc[mt][nt] = __builtin_amdgcn_mfma_f32_16x16x32_bf16(af[mt], bfr[nt], acc[mt][nt], 0, 0, 0);
    }

    #pragma unroll
    for (int mt = 0; mt < 4; mt++) {
        #pragma unroll
        for (int r = 0; r < 4; r++) {
            int m = m0 + wm * 64 + mt * 16 + quad * 4 + r;
            int b = m >> 10;
            float covv = ldmix(f32, cov, m);
            #pragma unroll
            for (int nt = 0; nt < 4; nt++) {
                int n = n0 + wn * 64 + nt * 16 + l16;
                float v = acc[mt][nt][r] + proj_dec[b * AA + n] + covv * ldmix(f32, Wcov, n);
                feats[(size_t)m * AA + n] = f2bf(fast_tanh(v));
            }
        }
    }
}

__global__ __launch_bounds__(256)
void k_gemm2(const ushort_t* __restrict__ Xg,
             const void* __restrict__ Bg,
             const void* __restrict__ b1,
             const void* __restrict__ wattn,
             const int* __restrict__ flagp,
             float* __restrict__ scores) {
    __shared__ ushort_t As[BM * BKP];
    __shared__ ushort_t Bs[BN * BKP];
    const int f32 = *flagp;
    const int tid = threadIdx.x;
    const int lane = tid & 63, wave = tid >> 6;
    const int quad = lane >> 4, l16 = lane & 15;
    const int wm = wave >> 1, wn = wave & 1;
    const int m0 = blockIdx.y * BM, n0 = blockIdx.x * BN;

    float4_t acc[4][4];
    #pragma unroll
    for (int i = 0; i < 4; i++)
        #pragma unroll
        for (int j = 0; j < 4; j++) acc[i][j] = (float4_t){0.f, 0.f, 0.f, 0.f};

    const int srow = lane >> 2;
    const int scol = (lane & 3) * 8;
    ushort_t* lA0 = &As[(wave * 32 + srow) * BKP + scol];
    ushort_t* lB0 = &Bs[(wave * 32 + srow) * BKP + scol];

    for (int kt = 0; kt < KK; kt += BK) {
        __syncthreads();
        stage8(0,   Xg, (long)(m0 + wave * 32 + srow), kt + scol, lA0);
        stage8(0,   Xg, (long)(m0 + wave * 32 + srow + 16), kt + scol, lA0 + 16 * BKP);
        stage8(f32, Bg, (long)(n0 + wave * 32 + srow), kt + scol, lB0);
        stage8(f32, Bg, (long)(n0 + wave * 32 + srow + 16), kt + scol, lB0 + 16 * BKP);
        __syncthreads();
        short8 af[4], bfr[4];
        #pragma unroll
        for (int mt = 0; mt < 4; mt++)
            af[mt] = *(const short8*)&As[(wm * 64 + mt * 16 + l16) * BKP + quad * 8];
        #pragma unroll
        for (int nt = 0; nt < 4; nt++)
            bfr[nt] = *(const short8*)&Bs[(wn * 64 + nt * 16 + l16) * BKP + quad * 8];
        #pragma unroll
        for (int mt = 0; mt < 4; mt++)
            #pragma unroll
            for (int nt = 0; nt < 4; nt++)
                acc[mt][nt] = __builtin_amdgcn_mfma_f32_16x16x32_bf16(af[mt], bfr[nt], acc[mt][nt], 0, 0, 0);
    }

    float wv[4], bv[4];
    #pragma unroll
    for (int nt = 0; nt < 4; nt++) {
        int n = n0 + wn * 64 + nt * 16 + l16;
        wv[nt] = ldmix(f32, wattn, n);
        bv[nt] = ldmix(f32, b1, n);
    }
    #pragma unroll
    for (int mt = 0; mt < 4; mt++) {
        #pragma unroll
        for (int r = 0; r < 4; r++) {
            int m = m0 + wm * 64 + mt * 16 + quad * 4 + r;
            float s = 0.f;
            #pragma unroll
            for (int nt = 0; nt < 4; nt++) {
                int n = n0 + wn * 64 + nt * 16 + l16;
                float v = acc[mt][nt][r] + bv[nt] + bf2f(Xg[(size_t)m * AA + n]);
                s += fast_tanh(v) * wv[nt];
            }
            s += __shfl_xor(s, 1);
            s += __shfl_xor(s, 2);
            s += __shfl_xor(s, 4);
            s += __shfl_xor(s, 8);
            if (l16 == 0) atomicAdd(&scores[m], s);
        }
    }
}

// ------------- bf16 GEMM1 v2: dbuf + counted vmcnt + T2 source/read swizzle -------------
// grid: 2048 blocks (1-D), bijective XCD swizzle (2048 = 8*256).
// LDS kept LINEAR for global_load_lds; swizzle applied by permuting the global
// SOURCE column (col ^= (row&7)*8 elems) and the ds_read address identically.
__global__ __launch_bounds__(256)
void k_gemm1n(const void* __restrict__ enc,
              const ushort_t* __restrict__ enc_bf,
              const ushort_t* __restrict__ Wenc_bf,
              const float* __restrict__ proj_dec,
              const void* __restrict__ cov,
              const void* __restrict__ Wcov,
              const int* __restrict__ flagp,
              ushort_t* __restrict__ feats) {
    __shared__ ushort_t As[2][BM * BK2];   // 2 x 16 KB
    __shared__ ushort_t Bs[2][BN * BK2];   // 2 x 16 KB
    const int f32 = *flagp;
    const ushort_t* Abf = f32 ? enc_bf : (const ushort_t*)enc;

    const int lid = ((blockIdx.x & 7) << 8) | (blockIdx.x >> 3);
    const int m0 = (lid >> 2) * BM;
    const int n0 = (lid & 3) * BN;

    const int tid = threadIdx.x;
    const int lane = tid & 63, wave = tid >> 6;
    const int quad = lane >> 4, l16 = lane & 15;
    const int wm = wave >> 1, wn = wave & 1;
    const int l8r = lane >> 3;                       // row within 8-row chunk (0..7)
    const int l8c = ((lane & 7) ^ l8r) * 8;          // pre-swizzled source column

    float4_t acc[4][4];
    #pragma unroll
    for (int i = 0; i < 4; i++)
        #pragma unroll
        for (int j = 0; j < 4; j++) acc[i][j] = (float4_t){0.f, 0.f, 0.f, 0.f};

    // per-tile stage: 8 global_load_lds per thread (4 A-chunks + 4 B-chunks)
    #define STAGE1(buf, kel)                                                              \
        _Pragma("unroll")                                                                 \
        for (int i = 0; i < 4; i++) {                                                     \
            int ch = i * 4 + wave;                                                        \
            glds16(Abf     + (((size_t)(m0 + ch * 8 + l8r)) << 9) + (kel) + l8c,          \
                   &As[buf][ch * 512]);                                                   \
            glds16(Wenc_bf + (((size_t)(n0 + ch * 8 + l8r)) << 9) + (kel) + l8c,          \
                   &Bs[buf][ch * 512]);                                                   \
        }

    #define COMPUTE1(buf)                                                                 \
        _Pragma("unroll")                                                                 \
        for (int kk = 0; kk < 2; kk++) {                                                  \
            short8 af[4], bfv[4];                                                         \
            _Pragma("unroll")                                                             \
            for (int mt = 0; mt < 4; mt++) {                                              \
                int row = wm * 64 + mt * 16 + l16;                                        \
                int col = (kk * 32 + quad * 8) ^ ((row & 7) << 3);                        \
                af[mt] = *(const short8*)&As[buf][row * BK2 + col];                       \
            }                                                                             \
            _Pragma("unroll")                                                             \
            for (int nt = 0; nt < 4; nt++) {                                              \
                int row = wn * 64 + nt * 16 + l16;                                        \
                int col = (kk * 32 + quad * 8) ^ ((row & 7) << 3);                        \
                bfv[nt] = *(const short8*)&Bs[buf][row * BK2 + col];                      \
            }                                                                             \
            _Pragma("unroll")                                                             \
            for (int mt = 0; mt < 4; mt++)                                                \
                _Pragma("unroll")                                                         \
                for (int nt = 0; nt < 4; nt++)                                            \
                    acc[mt][nt] = __builtin_amdgcn_mfma_f32_16x16x32_bf16(                \
                        af[mt], bfv[nt], acc[mt][nt], 0, 0, 0);                           \
        }

    STAGE1(0, 0);                       // prologue: tile 0 in flight
    #pragma unroll
    for (int kt = 0; kt < NT - 1; kt++) {
        const int cur = kt & 1;
        STAGE1(cur ^ 1, (kt + 1) * BK2);               // prefetch next tile (8 vmem)
        asm volatile("s_waitcnt vmcnt(8)" ::: "memory");  // cur tile landed (per-wave)
        __builtin_amdgcn_s_barrier();                     // all waves' cur writes visible
        COMPUTE1(cur);
        asm volatile("s_waitcnt lgkmcnt(0)" ::: "memory");
        __builtin_amdgcn_s_barrier();                     // all waves done reading cur
    }
    asm volatile("s_waitcnt vmcnt(0)" ::: "memory");
    __builtin_amdgcn_s_barrier();
    COMPUTE1((NT - 1) & 1);

    #undef STAGE1
    #undef COMPUTE1

    #pragma unroll
    for (int mt = 0; mt < 4; mt++) {
        #pragma unroll
        for (int r = 0; r < 4; r++) {
            int m = m0 + wm * 64 + mt * 16 + quad * 4 + r;
            int b = m >> 10;
            float covv = ldmix(f32, cov, m);
            #pragma unroll
            for (int nt = 0; nt < 4; nt++) {
                int n = n0 + wn * 64 + nt * 16 + l16;
                float v = acc[mt][nt][r] + proj_dec[b * AA + n] + covv * ldmix(f32, Wcov, n);
                feats[(size_t)m * AA + n] = f2bf(fast_tanh(v));
            }
        }
    }
}

// ------------- bf16 GEMM2 v2: same structure, feats @ W1^T -------------
__global__ __launch_bounds__(256)
void k_gemm2n(const ushort_t* __restrict__ Xg,      // feats (bf16)
              const ushort_t* __restrict__ W1_bf,
              const void* __restrict__ b1,
              const void* __restrict__ wattn,
              const int* __restrict__ flagp,
              float* __restrict__ scores) {
    __shared__ ushort_t As[2][BM * BK2];
    __shared__ ushort_t Bs[2][BN * BK2];
    const int f32 = *flagp;

    const int lid = ((blockIdx.x & 7) << 8) | (blockIdx.x >> 3);
    const int m0 = (lid >> 2) * BM;
    const int n0 = (lid & 3) * BN;

    const int tid = threadIdx.x;
    const int lane = tid & 63, wave = tid >> 6;
    const int quad = lane >> 4, l16 = lane & 15;
    const int wm = wave >> 1, wn = wave & 1;
    const int l8r = lane >> 3;
    const int l8c = ((lane & 7) ^ l8r) * 8;

    float4_t acc[4][4];
    #pragma unroll
    for (int i = 0; i < 4; i++)
        #pragma unroll
        for (int j = 0; j < 4; j++) acc[i][j] = (float4_t){0.f, 0.f, 0.f, 0.f};

    #define STAGE2(buf, kel)                                                              \
        _Pragma("unroll")                                                                 \
        for (int i = 0; i < 4; i++) {                                                     \
            int ch = i * 4 + wave;                                                        \
            glds16(Xg    + (((size_t)(m0 + ch * 8 + l8r)) << 9) + (kel) + l8c,            \
                   &As[buf][ch * 512]);                                                   \
            glds16(W1_bf + (((size_t)(n0 + ch * 8 + l8r)) << 9) + (kel) + l8c,            \
                   &Bs[buf][ch * 512]);                                                   \
        }

    #define COMPUTE2(buf)                                                                 \
        _Pragma("unroll")                                                                 \
        for (int kk = 0; kk < 2; kk++) {                                                  \
            short8 af[4], bfv[4];                                                         \
            _Pragma("unroll")                                                             \
            for (int mt = 0; mt < 4; mt++) {                                              \
                int row = wm * 64 + mt * 16 + l16;                                        \
                int col = (kk * 32 + quad * 8) ^ ((row & 7) << 3);                        \
                af[mt] = *(const short8*)&As[buf][row * BK2 + col];                       \
            }                                                                             \
            _Pragma("unroll")                                                             \
            for (int nt = 0; nt < 4; nt++) {                                              \
                int row = wn * 64 + nt * 16 + l16;                                        \
                int col = (kk * 32 + quad * 8) ^ ((row & 7) << 3);                        \
                bfv[nt] = *(const short8*)&Bs[buf][row * BK2 + col];                      \
            }                                                                             \
            _Pragma("unroll")                                                             \
            for (int mt = 0; mt < 4; mt++)                                                \
                _Pragma("unroll")                                                         \
                for (int nt = 0; nt < 4; nt++)                                            \
                    acc[mt][nt] = __builtin_amdgcn_mfma_f32_16x16x32_bf16(                \
                        af[mt], bfv[nt], acc[mt][nt], 0, 0, 0);                           \
        }

    STAGE2(0, 0);
    #pragma unroll
    for (int kt = 0; kt < NT - 1; kt++) {
        const int cur = kt & 1;
        STAGE2(cur ^ 1, (kt + 1) * BK2);
        asm volatile("s_waitcnt vmcnt(8)" ::: "memory");
        __builtin_amdgcn_s_barrier();
        COMPUTE2(cur);
        asm volatile("s_waitcnt lgkmcnt(0)" ::: "memory");
        __builtin_amdgcn_s_barrier();
    }
    asm volatile("s_waitcnt vmcnt(0)" ::: "memory");
    __builtin_amdgcn_s_barrier();
    COMPUTE2((NT - 1) & 1);

    #undef STAGE2
    #undef COMPUTE2

    float wv[4], bv[4];
    #pragma unroll
    for (int nt = 0; nt < 4; nt++) {
        int n = n0 + wn * 64 + nt * 16 + l16;
        wv[nt] = ldmix(f32, wattn, n);
        bv[nt] = ldmix(f32, b1, n);
    }
    #pragma unroll
    for (int mt = 0; mt < 4; mt++) {
        #pragma unroll
        for (int r = 0; r < 4; r++) {
            int m = m0 + wm * 64 + mt * 16 + quad * 4 + r;
            float s = 0.f;
            #pragma unroll
            for (int nt = 0; nt < 4; nt++) {
                int n = n0 + wn * 64 + nt * 16 + l16;
                float v = acc[mt][nt][r] + bv[nt] + bf2f(Xg[(size_t)m * AA + n]);
                s += fast_tanh(v) * wv[nt];
            }
            s += __shfl_xor(s, 1);
            s += __shfl_xor(s, 2);
            s += __shfl_xor(s, 4);
            s += __shfl_xor(s, 8);
            if (l16 == 0) atomicAdd(&scores[m], s);
        }
    }
}

__global__ void k_softmax(const float* __restrict__ scores,
                          const int* __restrict__ mask,
                          const void* __restrict__ cov,
                          const int* __restrict__ flagp,
                          float* __restrict__ attnw,
                          void* __restrict__ dout) {
    __shared__ float red[4];
    const int f32 = *flagp;
    int b = blockIdx.x, tid = threadIdx.x;
    float v[4];
    #pragma unroll
    for (int i = 0; i < 4; i++) {
        int s = tid + i * 256;
        float sc = scores[b * SS + s];
        if (mask[b * SS + s] == 0) sc = -1e9f;
        v[i] = sc;
    }
    float mx = fmaxf(fmaxf(v[0], v[1]), fmaxf(v[2], v[3]));
    #pragma unroll
    for (int off = 1; off < 64; off <<= 1) mx = fmaxf(mx, __shfl_xor(mx, off));
    if ((tid & 63) == 0) red[tid >> 6] = mx;
    __syncthreads();
    mx = fmaxf(fmaxf(red[0], red[1]), fmaxf(red[2], red[3]));
    __syncthreads();
    float e[4], sum = 0.f;
    #pragma unroll
    for (int i = 0; i < 4; i++) { e[i] = expf(v[i] - mx); sum += e[i]; }
    #pragma unroll
    for (int off = 1; off < 64; off <<= 1) sum += __shfl_xor(sum, off);
    if ((tid & 63) == 0) red[tid >> 6] = sum;
    __syncthreads();
    sum = red[0] + red[1] + red[2] + red[3];
    float inv = 1.0f / sum;
    #pragma unroll
    for (int i = 0; i < 4; i++) {
        int s = tid + i * 256;
        float w = e[i] * inv;
        attnw[b * SS + s] = w;
        stmix(f32, dout, 32768L + (long)b * SS + s, w);
        stmix(f32, dout, 98304L + (long)b * SS + s, ldmix(f32, cov, (long)b * SS + s) + w);
    }
}

__global__ void k_context(const void* __restrict__ enc,
                          const ushort_t* __restrict__ enc_bf,
                          const int pre,
                          const float* __restrict__ attnw,
                          const int* __restrict__ flagp,
                          float* __restrict__ ctx) {
    int f32 = *flagp;
    const void* e = enc;
    if (pre && f32) { e = enc_bf; f32 = 0; }   // use pre-converted bf16 copy
    int b = blockIdx.x, sc = blockIdx.y;
    int tid = threadIdx.x;
    float a0 = 0.f, a1 = 0.f;
    const float* wrow = attnw + b * SS + sc * 128;
    if (f32) {
        const float* base = (const float*)e + ((size_t)b * SS + sc * 128) * EE;
        for (int s = 0; s < 128; s++) {
            float w = wrow[s];
            float2_t u = *(const float2_t*)(base + (size_t)s * EE + 2 * tid);
            a0 += w * u[0];
            a1 += w * u[1];
        }
    } else {
        const unsigned int* base = (const unsigned int*)e + ((size_t)b * SS + sc * 128) * (EE / 2);
        for (int s = 0; s < 128; s++) {
            float w = wrow[s];
            unsigned int u = base[(size_t)s * (EE / 2) + tid];
            a0 += w * bf2f((ushort_t)(u & 0xffff));
            a1 += w * bf2f((ushort_t)(u >> 16));
        }
    }
    atomicAdd(&ctx[b * EE + 2 * tid], a0);
    atomicAdd(&ctx[b * EE + 2 * tid + 1], a1);
}

// ---------------- gate: wave-per-output. grid (A/4, B), 256 thr ----------------
__global__ __launch_bounds__(256)
void k_gate(const float* __restrict__ ctx,
            const void* __restrict__ dec,
            const void* __restrict__ Wg,
            const void* __restrict__ bg,
            const int* __restrict__ flagp,
            void* __restrict__ dout) {
    __shared__ float gin[EE + DD];
    const int f32 = *flagp;
    const int b = blockIdx.y;
    const int tid = threadIdx.x, lane = tid & 63, wave = tid >> 6;
    gin[2 * tid]     = ctx[b * EE + 2 * tid];
    gin[2 * tid + 1] = ctx[b * EE + 2 * tid + 1];
    gin[EE + tid]       = ldmix(f32, dec, (long)b * DD + tid);
    gin[EE + tid + 256] = ldmix(f32, dec, (long)b * DD + tid + 256);
    __syncthreads();
    const int a = blockIdx.x * 4 + wave;
    float s = 0.f;
    if (f32) {
        const float* wr = (const float*)Wg + (size_t)a * (EE + DD) + lane * 16;
        #pragma unroll
        for (int j = 0; j < 16; j++) s += wr[j] * gin[lane * 16 + j];
    } else {
        const ushort_t* wr = (const ushort_t*)Wg + (size_t)a * (EE + DD) + lane * 16;
        short8 w0 = *(const short8*)wr;
        short8 w1 = *(const short8*)(wr + 8);
        #pragma unroll
        for (int j = 0; j < 8; j++) {
            s += bf2f((ushort_t)w0[j]) * gin[lane * 16 + j];
            s += bf2f((ushort_t)w1[j]) * gin[lane * 16 + 8 + j];
        }
    }
    #pragma unroll
    for (int off = 1; off < 64; off <<= 1) s += __shfl_xor(s, off);
    if (lane == 0) {
        float acc = s + ldmix(f32, bg, a);
        float g = 1.f / (1.f + __expf(-acc));
        stmix(f32, dout, (long)b * AA + a, g * ctx[b * EE + a]);
    }
}

extern "C" void kernel_launch(void* const* d_in, const int* in_sizes, int n_in,
                              void* d_out, int out_size, void* d_ws, size_t ws_size,
                              hipStream_t stream) {
    const void* enc   = d_in[0];
    const void* dec   = d_in[1];
    const int*  mask  = (const int*)d_in[2];
    const void* cov   = d_in[3];
    const void* Wenc  = d_in[4];
    const void* Wdec  = d_in[5];
    const void* wattn = d_in[6];
    const void* Wl1   = d_in[7];
    const void* b1    = d_in[8];
    const void* Wcov  = d_in[9];
    const void* Wg    = d_in[10];
    const void* bg    = d_in[11];

    char* ws = (char*)d_ws;
    float*    scores = (float*)ws;                  // 262144 B
    float*    ctx    = (float*)(ws + 262144);       // 131072 B
    float*    attnw  = (float*)(ws + 393216);       // 262144 B
    float*    projd  = (float*)(ws + 655360);       // 131072 B
    int*      flag   = (int*)(ws + 786432);         // 4 B
    ushort_t* feats  = (ushort_t*)(ws + 1048576);   // 67108864 B -> ends 68157440
    ushort_t* W1b    = (ushort_t*)(ws + 68157440);  // 524288 B   -> ends 68681728
    ushort_t* Wencb  = (ushort_t*)(ws + 68681728);  // 524288 B   -> ends 69206016
    ushort_t* encb   = (ushort_t*)(ws + 69206016);  // 67108864 B -> ends 136314880
    const int pre2 = (ws_size >= 69206016UL)  ? 1 : 0;  // bf16 weight copies fit
    const int pre1 = (ws_size >= 136314880UL) ? 1 : 0;  // bf16 enc copy also fits

    hipMemsetAsync(ws, 0, 393216, stream);
    k_detect<<<1, 256, 0, stream>>>((const ushort_t*)enc, flag);
    if (pre2)
        k_conv_w<<<dim3(128, 2), 256, 0, stream>>>(Wenc, Wl1, flag, Wencb, W1b);
    if (pre1)
        k_conv_enc<<<4096, 256, 0, stream>>>(enc, flag, encb);
    k_proj_dec<<<dim3(AA / 4, BB), 256, 0, stream>>>(dec, Wdec, flag, projd);
    if (pre1)
        k_gemm1n<<<2048, 256, 0, stream>>>(enc, encb, Wencb, projd, cov, Wcov, flag, feats);
    else
        k_gemm1<<<dim3(AA / BN, MM / BM), 256, 0, stream>>>(enc, Wenc, projd, cov, Wcov, flag, feats);
    if (pre2)
        k_gemm2n<<<2048, 256, 0, stream>>>(feats, W1b, b1, wattn, flag, scores);
    else
        k_gemm2<<<dim3(AA / BN, MM / BM), 256, 0, stream>>>(feats, Wl1, b1, wattn, flag, scores);
    k_softmax<<<BB, 256, 0, stream>>>(scores, mask, cov, flag, attnw, d_out);
    k_context<<<dim3(BB, 8), 256, 0, stream>>>(enc, encb, pre1, attnw, flag, ctx);
    k_gate<<<dim3(AA / 4, BB), 256, 0, stream>>>(ctx, dec, Wg, bg, flag, d_out);
}

// Round 4
// 405.600 us; speedup vs baseline: 1.2619x; 1.0721x over previous
//
#include <hip/hip_runtime.h>
#include <hip/hip_bf16.h>

typedef unsigned short ushort_t;
typedef __attribute__((ext_vector_type(8))) short short8;
typedef __attribute__((ext_vector_type(4))) float float4_t;
typedef __attribute__((ext_vector_type(2))) float float2_t;
typedef __attribute__((ext_vector_type(4))) unsigned int uint4_t;

#define BB 64
#define SS 1024
#define EE 512
#define DD 512
#define AA 512
#define MM (BB*SS)
#define KK 512
#define BM 128
#define BN 128
#define BK 32
#define BKP 40   // padded LDS row stride for legacy kernels
#define BK2 64   // K-step for the global_load_lds GEMMs
#define NT (KK/BK2)

__device__ __forceinline__ float bf2f(ushort_t u) {
    return __uint_as_float(((unsigned int)u) << 16);
}
__device__ __forceinline__ ushort_t f2bf(float f) {
    unsigned int u = __float_as_uint(f);
    unsigned int r = u + 0x7fffu + ((u >> 16) & 1u);
    return (ushort_t)(r >> 16);
}
__device__ __forceinline__ float ldmix(int f32, const void* p, long idx) {
    return f32 ? ((const float*)p)[idx] : bf2f(((const ushort_t*)p)[idx]);
}
__device__ __forceinline__ void stmix(int f32, void* p, long idx, float v) {
    if (f32) ((float*)p)[idx] = v;
    else     ((ushort_t*)p)[idx] = f2bf(v);
}
__device__ __forceinline__ float fast_tanh(float x) {
    float e = __expf(2.f * x);
    return 1.f - 2.f / (e + 1.f);
}
// async global->LDS, 16B per lane. LDS ptr must be wave-uniform (HW adds lane*16B).
__device__ __forceinline__ void glds16(const ushort_t* g, ushort_t* l) {
    typedef __attribute__((address_space(1))) const void gas_t;
    typedef __attribute__((address_space(3))) void las_t;
    gas_t* gp = (gas_t*)g;
    las_t* lp = (las_t*)l;
    __builtin_amdgcn_global_load_lds(gp, lp, 16, 0, 0);
}

__global__ void k_detect(const ushort_t* __restrict__ enc, int* __restrict__ flag) {
    __shared__ int cnt;
    int tid = threadIdx.x;
    if (tid == 0) cnt = 0;
    __syncthreads();
    int c = 0;
    const uint4_t* p = (const uint4_t*)enc;
    for (int i = tid; i < 4096; i += 256) {
        uint4_t v = p[i];
        #pragma unroll
        for (int j = 0; j < 4; j++) {
            unsigned int u = v[j];
            if (((u >> 7) & 0xFFu) == 0xFFu || ((u >> 23) & 0xFFu) == 0xFFu) c++;
        }
    }
    atomicAdd(&cnt, c);
    __syncthreads();
    if (tid == 0) *flag = (cnt > 0) ? 1 : 0;
}

// -------- weight pre-convert: Wenc -> bf16, W1 -> bf16. grid (128, 2) --------
__global__ __launch_bounds__(256)
void k_conv_w(const void* __restrict__ Wenc, const void* __restrict__ W1,
              const int* __restrict__ flagp,
              ushort_t* __restrict__ WencB, ushort_t* __restrict__ W1B) {
    const int f32 = *flagp;
    const void* src = blockIdx.y ? W1 : Wenc;
    ushort_t* dst = blockIdx.y ? W1B : WencB;
    long e0 = ((long)blockIdx.x * 256 + threadIdx.x) * 8;
    short8 p;
    #pragma unroll
    for (int j = 0; j < 8; j++) p[j] = (short)f2bf(ldmix(f32, src, e0 + j));
    *(short8*)&dst[e0] = p;
}

// -------- enc pre-convert fp32 -> bf16 (only when input is fp32) --------
__global__ __launch_bounds__(256)
void k_conv_enc(const void* __restrict__ enc, const int* __restrict__ flagp,
                ushort_t* __restrict__ out) {
    if (*flagp == 0) return;   // already bf16; consumers read original pointer
    const float4_t* src = (const float4_t*)enc;
    size_t i0 = (size_t)blockIdx.x * 256 + threadIdx.x;
    size_t n8 = (size_t)MM * EE / 8;
    size_t stride = (size_t)gridDim.x * 256;
    for (size_t i = i0; i < n8; i += stride) {
        float4_t v0 = src[2 * i], v1 = src[2 * i + 1];
        short8 p;
        p[0] = (short)f2bf(v0[0]); p[1] = (short)f2bf(v0[1]);
        p[2] = (short)f2bf(v0[2]); p[3] = (short)f2bf(v0[3]);
        p[4] = (short)f2bf(v1[0]); p[5] = (short)f2bf(v1[1]);
        p[6] = (short)f2bf(v1[2]); p[7] = (short)f2bf(v1[3]);
        *(short8*)&out[i * 8] = p;
    }
}

// ---------------- proj_dec: wave-per-output. grid (A/4, B), 256 thr ----------------
__global__ __launch_bounds__(256)
void k_proj_dec(const void* __restrict__ dec,
                const void* __restrict__ Wdec,
                const int* __restrict__ flagp,
                float* __restrict__ proj) {
    __shared__ float x[DD];
    const int f32 = *flagp;
    const int b = blockIdx.y;
    const int tid = threadIdx.x, lane = tid & 63, wave = tid >> 6;
    x[tid]       = ldmix(f32, dec, (long)b * DD + tid);
    x[tid + 256] = ldmix(f32, dec, (long)b * DD + tid + 256);
    __syncthreads();
    const int a = blockIdx.x * 4 + wave;
    float s = 0.f;
    if (f32) {
        const float* wr = (const float*)Wdec + (size_t)a * DD + lane * 8;
        #pragma unroll
        for (int j = 0; j < 8; j++) s += wr[j] * x[lane * 8 + j];
    } else {
        const ushort_t* wr = (const ushort_t*)Wdec + (size_t)a * DD + lane * 8;
        short8 w = *(const short8*)wr;
        #pragma unroll
        for (int j = 0; j < 8; j++) s += bf2f((ushort_t)w[j]) * x[lane * 8 + j];
    }
    #pragma unroll
    for (int off = 1; off < 64; off <<= 1) s += __shfl_xor(s, off);
    if (lane == 0) proj[b * AA + a] = s;
}

// legacy register-staging (fallback path when workspace too small)
__device__ __forceinline__ void stage8(int f32, const void* g, long row, int col,
                                       ushort_t* lds) {
    if (f32) {
        const float* gf = (const float*)g + row * KK + col;
        float4_t v0 = *(const float4_t*)(gf);
        float4_t v1 = *(const float4_t*)(gf + 4);
        short8 p;
        p[0] = (short)f2bf(v0[0]); p[1] = (short)f2bf(v0[1]);
        p[2] = (short)f2bf(v0[2]); p[3] = (short)f2bf(v0[3]);
        p[4] = (short)f2bf(v1[0]); p[5] = (short)f2bf(v1[1]);
        p[6] = (short)f2bf(v1[2]); p[7] = (short)f2bf(v1[3]);
        *(short8*)lds = p;
    } else {
        const ushort_t* gb = (const ushort_t*)g + row * KK + col;
        *(short8*)lds = *(const short8*)gb;
    }
}

__global__ __launch_bounds__(256)
void k_gemm1(const void* __restrict__ Xg,
             const void* __restrict__ Bg,
             const float* __restrict__ proj_dec,
             const void* __restrict__ cov,
             const void* __restrict__ Wcov,
             const int* __restrict__ flagp,
             ushort_t* __restrict__ feats) {
    __shared__ ushort_t As[BM * BKP];
    __shared__ ushort_t Bs[BN * BKP];
    const int f32 = *flagp;
    const int tid = threadIdx.x;
    const int lane = tid & 63, wave = tid >> 6;
    const int quad = lane >> 4, l16 = lane & 15;
    const int wm = wave >> 1, wn = wave & 1;
    const int m0 = blockIdx.y * BM, n0 = blockIdx.x * BN;

    float4_t acc[4][4];
    #pragma unroll
    for (int i = 0; i < 4; i++)
        #pragma unroll
        for (int j = 0; j < 4; j++) acc[i][j] = (float4_t){0.f, 0.f, 0.f, 0.f};

    const int srow = lane >> 2;
    const int scol = (lane & 3) * 8;
    ushort_t* lA0 = &As[(wave * 32 + srow) * BKP + scol];
    ushort_t* lB0 = &Bs[(wave * 32 + srow) * BKP + scol];

    for (int kt = 0; kt < KK; kt += BK) {
        __syncthreads();
        stage8(f32, Xg, (long)(m0 + wave * 32 + srow), kt + scol, lA0);
        stage8(f32, Xg, (long)(m0 + wave * 32 + srow + 16), kt + scol, lA0 + 16 * BKP);
        stage8(f32, Bg, (long)(n0 + wave * 32 + srow), kt + scol, lB0);
        stage8(f32, Bg, (long)(n0 + wave * 32 + srow + 16), kt + scol, lB0 + 16 * BKP);
        __syncthreads();
        short8 af[4], bfr[4];
        #pragma unroll
        for (int mt = 0; mt < 4; mt++)
            af[mt] = *(const short8*)&As[(wm * 64 + mt * 16 + l16) * BKP + quad * 8];
        #pragma unroll
        for (int nt = 0; nt < 4; nt++)
            bfr[nt] = *(const short8*)&Bs[(wn * 64 + nt * 16 + l16) * BKP + quad * 8];
        #pragma unroll
        for (int mt = 0; mt < 4; mt++)
            #pragma unroll
            for (int nt = 0; nt < 4; nt++)
                acc[mt][nt] = __builtin_amdgcn_mfma_f32_16x16x32_bf16(af[mt], bfr[nt], acc[mt][nt], 0, 0, 0);
    }

    #pragma unroll
    for (int mt = 0; mt < 4; mt++) {
        #pragma unroll
        for (int r = 0; r < 4; r++) {
            int m = m0 + wm * 64 + mt * 16 + quad * 4 + r;
            int b = m >> 10;
            float covv = ldmix(f32, cov, m);
            #pragma unroll
            for (int nt = 0; nt < 4; nt++) {
                int n = n0 + wn * 64 + nt * 16 + l16;
                float v = acc[mt][nt][r] + proj_dec[b * AA + n] + covv * ldmix(f32, Wcov, n);
                feats[(size_t)m * AA + n] = f2bf(fast_tanh(v));
            }
        }
    }
}

__global__ __launch_bounds__(256)
void k_gemm2(const ushort_t* __restrict__ Xg,
             const void* __restrict__ Bg,
             const void* __restrict__ b1,
             const void* __restrict__ wattn,
             const int* __restrict__ flagp,
             float* __restrict__ scores) {
    __shared__ ushort_t As[BM * BKP];
    __shared__ ushort_t Bs[BN * BKP];
    const int f32 = *flagp;
    const int tid = threadIdx.x;
    const int lane = tid & 63, wave = tid >> 6;
    const int quad = lane >> 4, l16 = lane & 15;
    const int wm = wave >> 1, wn = wave & 1;
    const int m0 = blockIdx.y * BM, n0 = blockIdx.x * BN;

    float4_t acc[4][4];
    #pragma unroll
    for (int i = 0; i < 4; i++)
        #pragma unroll
        for (int j = 0; j < 4; j++) acc[i][j] = (float4_t){0.f, 0.f, 0.f, 0.f};

    const int srow = lane >> 2;
    const int scol = (lane & 3) * 8;
    ushort_t* lA0 = &As[(wave * 32 + srow) * BKP + scol];
    ushort_t* lB0 = &Bs[(wave * 32 + srow) * BKP + scol];

    for (int kt = 0; kt < KK; kt += BK) {
        __syncthreads();
        stage8(0,   Xg, (long)(m0 + wave * 32 + srow), kt + scol, lA0);
        stage8(0,   Xg, (long)(m0 + wave * 32 + srow + 16), kt + scol, lA0 + 16 * BKP);
        stage8(f32, Bg, (long)(n0 + wave * 32 + srow), kt + scol, lB0);
        stage8(f32, Bg, (long)(n0 + wave * 32 + srow + 16), kt + scol, lB0 + 16 * BKP);
        __syncthreads();
        short8 af[4], bfr[4];
        #pragma unroll
        for (int mt = 0; mt < 4; mt++)
            af[mt] = *(const short8*)&As[(wm * 64 + mt * 16 + l16) * BKP + quad * 8];
        #pragma unroll
        for (int nt = 0; nt < 4; nt++)
            bfr[nt] = *(const short8*)&Bs[(wn * 64 + nt * 16 + l16) * BKP + quad * 8];
        #pragma unroll
        for (int mt = 0; mt < 4; mt++)
            #pragma unroll
            for (int nt = 0; nt < 4; nt++)
                acc[mt][nt] = __builtin_amdgcn_mfma_f32_16x16x32_bf16(af[mt], bfr[nt], acc[mt][nt], 0, 0, 0);
    }

    float wv[4], bv[4];
    #pragma unroll
    for (int nt = 0; nt < 4; nt++) {
        int n = n0 + wn * 64 + nt * 16 + l16;
        wv[nt] = ldmix(f32, wattn, n);
        bv[nt] = ldmix(f32, b1, n);
    }
    #pragma unroll
    for (int mt = 0; mt < 4; mt++) {
        #pragma unroll
        for (int r = 0; r < 4; r++) {
            int m = m0 + wm * 64 + mt * 16 + quad * 4 + r;
            float s = 0.f;
            #pragma unroll
            for (int nt = 0; nt < 4; nt++) {
                int n = n0 + wn * 64 + nt * 16 + l16;
                float v = acc[mt][nt][r] + bv[nt] + bf2f(Xg[(size_t)m * AA + n]);
                s += fast_tanh(v) * wv[nt];
            }
            s += __shfl_xor(s, 1);
            s += __shfl_xor(s, 2);
            s += __shfl_xor(s, 4);
            s += __shfl_xor(s, 8);
            if (l16 == 0) atomicAdd(&scores[m], s);
        }
    }
}

// ------------- bf16 GEMM1 v3: single-buffer 32KB (m97 structure) + T2 swizzle -------------
// grid: 2048 blocks (1-D), bijective XCD swizzle (2048 = 8*256).
// LDS linear for global_load_lds; conflict-free via pre-swizzled global source col
// (col ^= (row&7)*8 elems) matched by the identical XOR on the ds_read address.
// Single 32KB buffer -> ~5 blocks/CU resident; simple 2-barrier loop (implicit
// wave-level overlap does the pipelining).
__global__ __launch_bounds__(256)
void k_gemm1n(const void* __restrict__ enc,
              const ushort_t* __restrict__ enc_bf,
              const ushort_t* __restrict__ Wenc_bf,
              const float* __restrict__ proj_dec,
              const void* __restrict__ cov,
              const void* __restrict__ Wcov,
              const int* __restrict__ flagp,
              ushort_t* __restrict__ feats) {
    __shared__ ushort_t As[BM * BK2];   // 16 KB
    __shared__ ushort_t Bs[BN * BK2];   // 16 KB
    const int f32 = *flagp;
    const ushort_t* Abf = f32 ? enc_bf : (const ushort_t*)enc;

    const int lid = ((blockIdx.x & 7) << 8) | (blockIdx.x >> 3);
    const int m0 = (lid >> 2) * BM;
    const int n0 = (lid & 3) * BN;

    const int tid = threadIdx.x;
    const int lane = tid & 63, wave = tid >> 6;
    const int quad = lane >> 4, l16 = lane & 15;
    const int wm = wave >> 1, wn = wave & 1;
    const int l8r = lane >> 3;                       // row within 8-row chunk (0..7)
    const int l8c = ((lane & 7) ^ l8r) * 8;          // pre-swizzled source column

    float4_t acc[4][4];
    #pragma unroll
    for (int i = 0; i < 4; i++)
        #pragma unroll
        for (int j = 0; j < 4; j++) acc[i][j] = (float4_t){0.f, 0.f, 0.f, 0.f};

    #pragma unroll
    for (int kt = 0; kt < NT; kt++) {
        __syncthreads();                     // prior iter's reads done before overwrite
        #pragma unroll
        for (int i = 0; i < 4; i++) {
            int ch = i * 4 + wave;           // 16 chunks of 8 rows x 64 cols (1 KB each)
            glds16(Abf     + (((size_t)(m0 + ch * 8 + l8r)) << 9) + kt * BK2 + l8c, &As[ch * 512]);
            glds16(Wenc_bf + (((size_t)(n0 + ch * 8 + l8r)) << 9) + kt * BK2 + l8c, &Bs[ch * 512]);
        }
        __syncthreads();                     // compiler drains vmcnt before barrier
        #pragma unroll
        for (int kk = 0; kk < 2; kk++) {
            short8 af[4], bfv[4];
            #pragma unroll
            for (int mt = 0; mt < 4; mt++) {
                int row = wm * 64 + mt * 16 + l16;
                int col = (kk * 32 + quad * 8) ^ ((row & 7) << 3);
                af[mt] = *(const short8*)&As[row * BK2 + col];
            }
            #pragma unroll
            for (int nt = 0; nt < 4; nt++) {
                int row = wn * 64 + nt * 16 + l16;
                int col = (kk * 32 + quad * 8) ^ ((row & 7) << 3);
                bfv[nt] = *(const short8*)&Bs[row * BK2 + col];
            }
            #pragma unroll
            for (int mt = 0; mt < 4; mt++)
                #pragma unroll
                for (int nt = 0; nt < 4; nt++)
                    acc[mt][nt] = __builtin_amdgcn_mfma_f32_16x16x32_bf16(af[mt], bfv[nt], acc[mt][nt], 0, 0, 0);
        }
    }

    // ---- epilogue: bounce the 128x128 bf16 tile through the (now-dead) LDS ----
    // rows 0..63 live in As, 64..127 in Bs (wm selects the half directly).
    __syncthreads();   // all LDS reads of the K-loop done before reuse
    ushort_t* myhalf = wm ? Bs : As;
    #pragma unroll
    for (int mt = 0; mt < 4; mt++) {
        #pragma unroll
        for (int r = 0; r < 4; r++) {
            int lr = mt * 16 + quad * 4 + r;         // row within this wave's half (0..63)
            int grow = wm * 64 + lr;                 // row within the 128-tile
            int m = m0 + grow;
            int b = m >> 10;
            float covv = ldmix(f32, cov, m);
            #pragma unroll
            for (int nt = 0; nt < 4; nt++) {
                int lc = wn * 64 + nt * 16 + l16;    // col within the 128-tile
                int n = n0 + lc;
                float v = acc[mt][nt][r] + proj_dec[b * AA + n] + covv * ldmix(f32, Wcov, n);
                myhalf[lr * 128 + (lc ^ ((grow & 7) << 3))] = f2bf(fast_tanh(v));
            }
        }
    }
    __syncthreads();
    #pragma unroll
    for (int rep = 0; rep < 8; rep++) {
        int row = rep * 16 + (tid >> 4);             // 0..127, each exactly once
        int c8 = (tid & 15) * 8;                     // 8-aligned col chunk
        const ushort_t* half = (row < 64) ? As : Bs;
        short8 vv = *(const short8*)&half[(row & 63) * 128 + (c8 ^ ((row & 7) << 3))];
        *(short8*)&feats[(size_t)(m0 + row) * AA + n0 + c8] = vv;
    }
}

// ------------- bf16 GEMM2 v3: same single-buffer structure, feats @ W1^T -------------
__global__ __launch_bounds__(256)
void k_gemm2n(const ushort_t* __restrict__ Xg,      // feats (bf16)
              const ushort_t* __restrict__ W1_bf,
              const void* __restrict__ b1,
              const void* __restrict__ wattn,
              const int* __restrict__ flagp,
              float* __restrict__ scores) {
    __shared__ ushort_t As[BM * BK2];
    __shared__ ushort_t Bs[BN * BK2];
    const int f32 = *flagp;

    const int lid = ((blockIdx.x & 7) << 8) | (blockIdx.x >> 3);
    const int m0 = (lid >> 2) * BM;
    const int n0 = (lid & 3) * BN;

    const int tid = threadIdx.x;
    const int lane = tid & 63, wave = tid >> 6;
    const int quad = lane >> 4, l16 = lane & 15;
    const int wm = wave >> 1, wn = wave & 1;
    const int l8r = lane >> 3;
    const int l8c = ((lane & 7) ^ l8r) * 8;

    float4_t acc[4][4];
    #pragma unroll
    for (int i = 0; i < 4; i++)
        #pragma unroll
        for (int j = 0; j < 4; j++) acc[i][j] = (float4_t){0.f, 0.f, 0.f, 0.f};

    #pragma unroll
    for (int kt = 0; kt < NT; kt++) {
        __syncthreads();
        #pragma unroll
        for (int i = 0; i < 4; i++) {
            int ch = i * 4 + wave;
            glds16(Xg    + (((size_t)(m0 + ch * 8 + l8r)) << 9) + kt * BK2 + l8c, &As[ch * 512]);
            glds16(W1_bf + (((size_t)(n0 + ch * 8 + l8r)) << 9) + kt * BK2 + l8c, &Bs[ch * 512]);
        }
        __syncthreads();
        #pragma unroll
        for (int kk = 0; kk < 2; kk++) {
            short8 af[4], bfv[4];
            #pragma unroll
            for (int mt = 0; mt < 4; mt++) {
                int row = wm * 64 + mt * 16 + l16;
                int col = (kk * 32 + quad * 8) ^ ((row & 7) << 3);
                af[mt] = *(const short8*)&As[row * BK2 + col];
            }
            #pragma unroll
            for (int nt = 0; nt < 4; nt++) {
                int row = wn * 64 + nt * 16 + l16;
                int col = (kk * 32 + quad * 8) ^ ((row & 7) << 3);
                bfv[nt] = *(const short8*)&Bs[row * BK2 + col];
            }
            #pragma unroll
            for (int mt = 0; mt < 4; mt++)
                #pragma unroll
                for (int nt = 0; nt < 4; nt++)
                    acc[mt][nt] = __builtin_amdgcn_mfma_f32_16x16x32_bf16(af[mt], bfv[nt], acc[mt][nt], 0, 0, 0);
        }
    }

    float wv[4], bv[4];
    #pragma unroll
    for (int nt = 0; nt < 4; nt++) {
        int n = n0 + wn * 64 + nt * 16 + l16;
        wv[nt] = ldmix(f32, wattn, n);
        bv[nt] = ldmix(f32, b1, n);
    }
    #pragma unroll
    for (int mt = 0; mt < 4; mt++) {
        #pragma unroll
        for (int r = 0; r < 4; r++) {
            int m = m0 + wm * 64 + mt * 16 + quad * 4 + r;
            float s = 0.f;
            #pragma unroll
            for (int nt = 0; nt < 4; nt++) {
                int n = n0 + wn * 64 + nt * 16 + l16;
                float v = acc[mt][nt][r] + bv[nt] + bf2f(Xg[(size_t)m * AA + n]);
                s += fast_tanh(v) * wv[nt];
            }
            s += __shfl_xor(s, 1);
            s += __shfl_xor(s, 2);
            s += __shfl_xor(s, 4);
            s += __shfl_xor(s, 8);
            if (l16 == 0) atomicAdd(&scores[m], s);
        }
    }
}

__global__ void k_softmax(const float* __restrict__ scores,
                          const int* __restrict__ mask,
                          const void* __restrict__ cov,
                          const int* __restrict__ flagp,
                          float* __restrict__ attnw,
                          void* __restrict__ dout) {
    __shared__ float red[4];
    const int f32 = *flagp;
    int b = blockIdx.x, tid = threadIdx.x;
    float v[4];
    #pragma unroll
    for (int i = 0; i < 4; i++) {
        int s = tid + i * 256;
        float sc = scores[b * SS + s];
        if (mask[b * SS + s] == 0) sc = -1e9f;
        v[i] = sc;
    }
    float mx = fmaxf(fmaxf(v[0], v[1]), fmaxf(v[2], v[3]));
    #pragma unroll
    for (int off = 1; off < 64; off <<= 1) mx = fmaxf(mx, __shfl_xor(mx, off));
    if ((tid & 63) == 0) red[tid >> 6] = mx;
    __syncthreads();
    mx = fmaxf(fmaxf(red[0], red[1]), fmaxf(red[2], red[3]));
    __syncthreads();
    float e[4], sum = 0.f;
    #pragma unroll
    for (int i = 0; i < 4; i++) { e[i] = expf(v[i] - mx); sum += e[i]; }
    #pragma unroll
    for (int off = 1; off < 64; off <<= 1) sum += __shfl_xor(sum, off);
    if ((tid & 63) == 0) red[tid >> 6] = sum;
    __syncthreads();
    sum = red[0] + red[1] + red[2] + red[3];
    float inv = 1.0f / sum;
    #pragma unroll
    for (int i = 0; i < 4; i++) {
        int s = tid + i * 256;
        float w = e[i] * inv;
        attnw[b * SS + s] = w;
        stmix(f32, dout, 32768L + (long)b * SS + s, w);
        stmix(f32, dout, 98304L + (long)b * SS + s, ldmix(f32, cov, (long)b * SS + s) + w);
    }
}

__global__ void k_context(const void* __restrict__ enc,
                          const ushort_t* __restrict__ enc_bf,
                          const int pre,
                          const float* __restrict__ attnw,
                          const int* __restrict__ flagp,
                          float* __restrict__ ctx) {
    int f32 = *flagp;
    const void* e = enc;
    if (pre && f32) { e = enc_bf; f32 = 0; }   // use pre-converted bf16 copy
    int b = blockIdx.x, sc = blockIdx.y;
    int tid = threadIdx.x;
    float a0 = 0.f, a1 = 0.f;
    const float* wrow = attnw + b * SS + sc * 128;
    if (f32) {
        const float* base = (const float*)e + ((size_t)b * SS + sc * 128) * EE;
        for (int s = 0; s < 128; s++) {
            float w = wrow[s];
            float2_t u = *(const float2_t*)(base + (size_t)s * EE + 2 * tid);
            a0 += w * u[0];
            a1 += w * u[1];
        }
    } else {
        const unsigned int* base = (const unsigned int*)e + ((size_t)b * SS + sc * 128) * (EE / 2);
        for (int s = 0; s < 128; s++) {
            float w = wrow[s];
            unsigned int u = base[(size_t)s * (EE / 2) + tid];
            a0 += w * bf2f((ushort_t)(u & 0xffff));
            a1 += w * bf2f((ushort_t)(u >> 16));
        }
    }
    atomicAdd(&ctx[b * EE + 2 * tid], a0);
    atomicAdd(&ctx[b * EE + 2 * tid + 1], a1);
}

// ---------------- gate: wave-per-output. grid (A/4, B), 256 thr ----------------
__global__ __launch_bounds__(256)
void k_gate(const float* __restrict__ ctx,
            const void* __restrict__ dec,
            const void* __restrict__ Wg,
            const void* __restrict__ bg,
            const int* __restrict__ flagp,
            void* __restrict__ dout) {
    __shared__ float gin[EE + DD];
    const int f32 = *flagp;
    const int b = blockIdx.y;
    const int tid = threadIdx.x, lane = tid & 63, wave = tid >> 6;
    gin[2 * tid]     = ctx[b * EE + 2 * tid];
    gin[2 * tid + 1] = ctx[b * EE + 2 * tid + 1];
    gin[EE + tid]       = ldmix(f32, dec, (long)b * DD + tid);
    gin[EE + tid + 256] = ldmix(f32, dec, (long)b * DD + tid + 256);
    __syncthreads();
    const int a = blockIdx.x * 4 + wave;
    float s = 0.f;
    if (f32) {
        const float* wr = (const float*)Wg + (size_t)a * (EE + DD) + lane * 16;
        #pragma unroll
        for (int j = 0; j < 16; j++) s += wr[j] * gin[lane * 16 + j];
    } else {
        const ushort_t* wr = (const ushort_t*)Wg + (size_t)a * (EE + DD) + lane * 16;
        short8 w0 = *(const short8*)wr;
        short8 w1 = *(const short8*)(wr + 8);
        #pragma unroll
        for (int j = 0; j < 8; j++) {
            s += bf2f((ushort_t)w0[j]) * gin[lane * 16 + j];
            s += bf2f((ushort_t)w1[j]) * gin[lane * 16 + 8 + j];
        }
    }
    #pragma unroll
    for (int off = 1; off < 64; off <<= 1) s += __shfl_xor(s, off);
    if (lane == 0) {
        float acc = s + ldmix(f32, bg, a);
        float g = 1.f / (1.f + __expf(-acc));
        stmix(f32, dout, (long)b * AA + a, g * ctx[b * EE + a]);
    }
}

extern "C" void kernel_launch(void* const* d_in, const int* in_sizes, int n_in,
                              void* d_out, int out_size, void* d_ws, size_t ws_size,
                              hipStream_t stream) {
    const void* enc   = d_in[0];
    const void* dec   = d_in[1];
    const int*  mask  = (const int*)d_in[2];
    const void* cov   = d_in[3];
    const void* Wenc  = d_in[4];
    const void* Wdec  = d_in[5];
    const void* wattn = d_in[6];
    const void* Wl1   = d_in[7];
    const void* b1    = d_in[8];
    const void* Wcov  = d_in[9];
    const void* Wg    = d_in[10];
    const void* bg    = d_in[11];

    char* ws = (char*)d_ws;
    float*    scores = (float*)ws;                  // 262144 B
    float*    ctx    = (float*)(ws + 262144);       // 131072 B
    float*    attnw  = (float*)(ws + 393216);       // 262144 B
    float*    projd  = (float*)(ws + 655360);       // 131072 B
    int*      flag   = (int*)(ws + 786432);         // 4 B
    ushort_t* feats  = (ushort_t*)(ws + 1048576);   // 67108864 B -> ends 68157440
    ushort_t* W1b    = (ushort_t*)(ws + 68157440);  // 524288 B   -> ends 68681728
    ushort_t* Wencb  = (ushort_t*)(ws + 68681728);  // 524288 B   -> ends 69206016
    ushort_t* encb   = (ushort_t*)(ws + 69206016);  // 67108864 B -> ends 136314880
    const int pre2 = (ws_size >= 69206016UL)  ? 1 : 0;  // bf16 weight copies fit
    const int pre1 = (ws_size >= 136314880UL) ? 1 : 0;  // bf16 enc copy also fits

    hipMemsetAsync(ws, 0, 393216, stream);
    k_detect<<<1, 256, 0, stream>>>((const ushort_t*)enc, flag);
    if (pre2)
        k_conv_w<<<dim3(128, 2), 256, 0, stream>>>(Wenc, Wl1, flag, Wencb, W1b);
    if (pre1)
        k_conv_enc<<<4096, 256, 0, stream>>>(enc, flag, encb);
    k_proj_dec<<<dim3(AA / 4, BB), 256, 0, stream>>>(dec, Wdec, flag, projd);
    if (pre1)
        k_gemm1n<<<2048, 256, 0, stream>>>(enc, encb, Wencb, projd, cov, Wcov, flag, feats);
    else
        k_gemm1<<<dim3(AA / BN, MM / BM), 256, 0, stream>>>(enc, Wenc, projd, cov, Wcov, flag, feats);
    if (pre2)
        k_gemm2n<<<2048, 256, 0, stream>>>(feats, W1b, b1, wattn, flag, scores);
    else
        k_gemm2<<<dim3(AA / BN, MM / BM), 256, 0, stream>>>(feats, Wl1, b1, wattn, flag, scores);
    k_softmax<<<BB, 256, 0, stream>>>(scores, mask, cov, flag, attnw, d_out);
    k_context<<<dim3(BB, 8), 256, 0, stream>>>(enc, encb, pre1, attnw, flag, ctx);
    k_gate<<<dim3(AA / 4, BB), 256, 0, stream>>>(ctx, dec, Wg, bg, flag, d_out);
}

// Round 7
// 399.637 us; speedup vs baseline: 1.2808x; 1.0149x over previous
//
#include <hip/hip_runtime.h>
#include <hip/hip_bf16.h>

typedef unsigned short ushort_t;
typedef __attribute__((ext_vector_type(8))) short short8;
typedef __attribute__((ext_vector_type(4))) float float4_t;
typedef __attribute__((ext_vector_type(2))) float float2_t;
typedef __attribute__((ext_vector_type(4))) unsigned int uint4_t;

#define BB 64
#define SS 1024
#define EE 512
#define DD 512
#define AA 512
#define MM (BB*SS)
#define KK 512
#define BM 128
#define BN 128
#define BK 32
#define BKP 40   // padded LDS row stride for legacy kernels
#define BK2 64   // K-step for the global_load_lds GEMMs
#define NT (KK/BK2)

__device__ __forceinline__ float bf2f(ushort_t u) {
    return __uint_as_float(((unsigned int)u) << 16);
}
__device__ __forceinline__ ushort_t f2bf(float f) {
    unsigned int u = __float_as_uint(f);
    unsigned int r = u + 0x7fffu + ((u >> 16) & 1u);
    return (ushort_t)(r >> 16);
}
__device__ __forceinline__ float ldmix(int f32, const void* p, long idx) {
    return f32 ? ((const float*)p)[idx] : bf2f(((const ushort_t*)p)[idx]);
}
__device__ __forceinline__ void stmix(int f32, void* p, long idx, float v) {
    if (f32) ((float*)p)[idx] = v;
    else     ((ushort_t*)p)[idx] = f2bf(v);
}
__device__ __forceinline__ float fast_tanh(float x) {
    float e = __expf(2.f * x);
    return 1.f - 2.f / (e + 1.f);
}
// async global->LDS, 16B per lane. LDS ptr must be wave-uniform (HW adds lane*16B).
__device__ __forceinline__ void glds16(const ushort_t* g, ushort_t* l) {
    typedef __attribute__((address_space(1))) const void gas_t;
    typedef __attribute__((address_space(3))) void las_t;
    gas_t* gp = (gas_t*)g;
    las_t* lp = (las_t*)l;
    __builtin_amdgcn_global_load_lds(gp, lp, 16, 0, 0);
}

__global__ void k_detect(const ushort_t* __restrict__ enc, int* __restrict__ flag) {
    __shared__ int cnt;
    int tid = threadIdx.x;
    if (tid == 0) cnt = 0;
    __syncthreads();
    int c = 0;
    const uint4_t* p = (const uint4_t*)enc;
    for (int i = tid; i < 4096; i += 256) {
        uint4_t v = p[i];
        #pragma unroll
        for (int j = 0; j < 4; j++) {
            unsigned int u = v[j];
            if (((u >> 7) & 0xFFu) == 0xFFu || ((u >> 23) & 0xFFu) == 0xFFu) c++;
        }
    }
    atomicAdd(&cnt, c);
    __syncthreads();
    if (tid == 0) *flag = (cnt > 0) ? 1 : 0;
}

// -------- weight pre-convert: Wenc -> bf16, W1 -> bf16. grid (128, 2) --------
__global__ __launch_bounds__(256)
void k_conv_w(const void* __restrict__ Wenc, const void* __restrict__ W1,
              const int* __restrict__ flagp,
              ushort_t* __restrict__ WencB, ushort_t* __restrict__ W1B) {
    const int f32 = *flagp;
    const void* src = blockIdx.y ? W1 : Wenc;
    ushort_t* dst = blockIdx.y ? W1B : WencB;
    long e0 = ((long)blockIdx.x * 256 + threadIdx.x) * 8;
    short8 p;
    #pragma unroll
    for (int j = 0; j < 8; j++) p[j] = (short)f2bf(ldmix(f32, src, e0 + j));
    *(short8*)&dst[e0] = p;
}

// -------- enc pre-convert fp32 -> bf16 (only when input is fp32) --------
__global__ __launch_bounds__(256)
void k_conv_enc(const void* __restrict__ enc, const int* __restrict__ flagp,
                ushort_t* __restrict__ out) {
    if (*flagp == 0) return;   // already bf16; consumers read original pointer
    const float4_t* src = (const float4_t*)enc;
    size_t i0 = (size_t)blockIdx.x * 256 + threadIdx.x;
    size_t n8 = (size_t)MM * EE / 8;
    size_t stride = (size_t)gridDim.x * 256;
    for (size_t i = i0; i < n8; i += stride) {
        float4_t v0 = src[2 * i], v1 = src[2 * i + 1];
        short8 p;
        p[0] = (short)f2bf(v0[0]); p[1] = (short)f2bf(v0[1]);
        p[2] = (short)f2bf(v0[2]); p[3] = (short)f2bf(v0[3]);
        p[4] = (short)f2bf(v1[0]); p[5] = (short)f2bf(v1[1]);
        p[6] = (short)f2bf(v1[2]); p[7] = (short)f2bf(v1[3]);
        *(short8*)&out[i * 8] = p;
    }
}

// ---------------- proj_dec: wave-per-output. grid (A/4, B), 256 thr ----------------
__global__ __launch_bounds__(256)
void k_proj_dec(const void* __restrict__ dec,
                const void* __restrict__ Wdec,
                const int* __restrict__ flagp,
                float* __restrict__ proj) {
    __shared__ float x[DD];
    const int f32 = *flagp;
    const int b = blockIdx.y;
    const int tid = threadIdx.x, lane = tid & 63, wave = tid >> 6;
    x[tid]       = ldmix(f32, dec, (long)b * DD + tid);
    x[tid + 256] = ldmix(f32, dec, (long)b * DD + tid + 256);
    __syncthreads();
    const int a = blockIdx.x * 4 + wave;
    float s = 0.f;
    if (f32) {
        const float* wr = (const float*)Wdec + (size_t)a * DD + lane * 8;
        #pragma unroll
        for (int j = 0; j < 8; j++) s += wr[j] * x[lane * 8 + j];
    } else {
        const ushort_t* wr = (const ushort_t*)Wdec + (size_t)a * DD + lane * 8;
        short8 w = *(const short8*)wr;
        #pragma unroll
        for (int j = 0; j < 8; j++) s += bf2f((ushort_t)w[j]) * x[lane * 8 + j];
    }
    #pragma unroll
    for (int off = 1; off < 64; off <<= 1) s += __shfl_xor(s, off);
    if (lane == 0) proj[b * AA + a] = s;
}

// legacy register-staging (fallback path when workspace too small)
__device__ __forceinline__ void stage8(int f32, const void* g, long row, int col,
                                       ushort_t* lds) {
    if (f32) {
        const float* gf = (const float*)g + row * KK + col;
        float4_t v0 = *(const float4_t*)(gf);
        float4_t v1 = *(const float4_t*)(gf + 4);
        short8 p;
        p[0] = (short)f2bf(v0[0]); p[1] = (short)f2bf(v0[1]);
        p[2] = (short)f2bf(v0[2]); p[3] = (short)f2bf(v0[3]);
        p[4] = (short)f2bf(v1[0]); p[5] = (short)f2bf(v1[1]);
        p[6] = (short)f2bf(v1[2]); p[7] = (short)f2bf(v1[3]);
        *(short8*)lds = p;
    } else {
        const ushort_t* gb = (const ushort_t*)g + row * KK + col;
        *(short8*)lds = *(const short8*)gb;
    }
}

__global__ __launch_bounds__(256)
void k_gemm1(const void* __restrict__ Xg,
             const void* __restrict__ Bg,
             const float* __restrict__ proj_dec,
             const void* __restrict__ cov,
             const void* __restrict__ Wcov,
             const int* __restrict__ flagp,
             ushort_t* __restrict__ feats) {
    __shared__ ushort_t As[BM * BKP];
    __shared__ ushort_t Bs[BN * BKP];
    const int f32 = *flagp;
    const int tid = threadIdx.x;
    const int lane = tid & 63, wave = tid >> 6;
    const int quad = lane >> 4, l16 = lane & 15;
    const int wm = wave >> 1, wn = wave & 1;
    const int m0 = blockIdx.y * BM, n0 = blockIdx.x * BN;

    float4_t acc[4][4];
    #pragma unroll
    for (int i = 0; i < 4; i++)
        #pragma unroll
        for (int j = 0; j < 4; j++) acc[i][j] = (float4_t){0.f, 0.f, 0.f, 0.f};

    const int srow = lane >> 2;
    const int scol = (lane & 3) * 8;
    ushort_t* lA0 = &As[(wave * 32 + srow) * BKP + scol];
    ushort_t* lB0 = &Bs[(wave * 32 + srow) * BKP + scol];

    for (int kt = 0; kt < KK; kt += BK) {
        __syncthreads();
        stage8(f32, Xg, (long)(m0 + wave * 32 + srow), kt + scol, lA0);
        stage8(f32, Xg, (long)(m0 + wave * 32 + srow + 16), kt + scol, lA0 + 16 * BKP);
        stage8(f32, Bg, (long)(n0 + wave * 32 + srow), kt + scol, lB0);
        stage8(f32, Bg, (long)(n0 + wave * 32 + srow + 16), kt + scol, lB0 + 16 * BKP);
        __syncthreads();
        short8 af[4], bfr[4];
        #pragma unroll
        for (int mt = 0; mt < 4; mt++)
            af[mt] = *(const short8*)&As[(wm * 64 + mt * 16 + l16) * BKP + quad * 8];
        #pragma unroll
        for (int nt = 0; nt < 4; nt++)
            bfr[nt] = *(const short8*)&Bs[(wn * 64 + nt * 16 + l16) * BKP + quad * 8];
        #pragma unroll
        for (int mt = 0; mt < 4; mt++)
            #pragma unroll
            for (int nt = 0; nt < 4; nt++)
                acc[mt][nt] = __builtin_amdgcn_mfma_f32_16x16x32_bf16(af[mt], bfr[nt], acc[mt][nt], 0, 0, 0);
    }

    #pragma unroll
    for (int mt = 0; mt < 4; mt++) {
        #pragma unroll
        for (int r = 0; r < 4; r++) {
            int m = m0 + wm * 64 + mt * 16 + quad * 4 + r;
            int b = m >> 10;
            float covv = ldmix(f32, cov, m);
            #pragma unroll
            for (int nt = 0; nt < 4; nt++) {
                int n = n0 + wn * 64 + nt * 16 + l16;
                float v = acc[mt][nt][r] + proj_dec[b * AA + n] + covv * ldmix(f32, Wcov, n);
                feats[(size_t)m * AA + n] = f2bf(fast_tanh(v));
            }
        }
    }
}

__global__ __launch_bounds__(256)
void k_gemm2(const ushort_t* __restrict__ Xg,
             const void* __restrict__ Bg,
             const void* __restrict__ b1,
             const void* __restrict__ wattn,
             const int* __restrict__ flagp,
             float* __restrict__ scores) {
    __shared__ ushort_t As[BM * BKP];
    __shared__ ushort_t Bs[BN * BKP];
    const int f32 = *flagp;
    const int tid = threadIdx.x;
    const int lane = tid & 63, wave = tid >> 6;
    const int quad = lane >> 4, l16 = lane & 15;
    const int wm = wave >> 1, wn = wave & 1;
    const int m0 = blockIdx.y * BM, n0 = blockIdx.x * BN;

    float4_t acc[4][4];
    #pragma unroll
    for (int i = 0; i < 4; i++)
        #pragma unroll
        for (int j = 0; j < 4; j++) acc[i][j] = (float4_t){0.f, 0.f, 0.f, 0.f};

    const int srow = lane >> 2;
    const int scol = (lane & 3) * 8;
    ushort_t* lA0 = &As[(wave * 32 + srow) * BKP + scol];
    ushort_t* lB0 = &Bs[(wave * 32 + srow) * BKP + scol];

    for (int kt = 0; kt < KK; kt += BK) {
        __syncthreads();
        stage8(0,   Xg, (long)(m0 + wave * 32 + srow), kt + scol, lA0);
        stage8(0,   Xg, (long)(m0 + wave * 32 + srow + 16), kt + scol, lA0 + 16 * BKP);
        stage8(f32, Bg, (long)(n0 + wave * 32 + srow), kt + scol, lB0);
        stage8(f32, Bg, (long)(n0 + wave * 32 + srow + 16), kt + scol, lB0 + 16 * BKP);
        __syncthreads();
        short8 af[4], bfr[4];
        #pragma unroll
        for (int mt = 0; mt < 4; mt++)
            af[mt] = *(const short8*)&As[(wm * 64 + mt * 16 + l16) * BKP + quad * 8];
        #pragma unroll
        for (int nt = 0; nt < 4; nt++)
            bfr[nt] = *(const short8*)&Bs[(wn * 64 + nt * 16 + l16) * BKP + quad * 8];
        #pragma unroll
        for (int mt = 0; mt < 4; mt++)
            #pragma unroll
            for (int nt = 0; nt < 4; nt++)
                acc[mt][nt] = __builtin_amdgcn_mfma_f32_16x16x32_bf16(af[mt], bfr[nt], acc[mt][nt], 0, 0, 0);
    }

    float wv[4], bv[4];
    #pragma unroll
    for (int nt = 0; nt < 4; nt++) {
        int n = n0 + wn * 64 + nt * 16 + l16;
        wv[nt] = ldmix(f32, wattn, n);
        bv[nt] = ldmix(f32, b1, n);
    }
    #pragma unroll
    for (int mt = 0; mt < 4; mt++) {
        #pragma unroll
        for (int r = 0; r < 4; r++) {
            int m = m0 + wm * 64 + mt * 16 + quad * 4 + r;
            float s = 0.f;
            #pragma unroll
            for (int nt = 0; nt < 4; nt++) {
                int n = n0 + wn * 64 + nt * 16 + l16;
                float v = acc[mt][nt][r] + bv[nt] + bf2f(Xg[(size_t)m * AA + n]);
                s += fast_tanh(v) * wv[nt];
            }
            s += __shfl_xor(s, 1);
            s += __shfl_xor(s, 2);
            s += __shfl_xor(s, 4);
            s += __shfl_xor(s, 8);
            if (l16 == 0) atomicAdd(&scores[m], s);
        }
    }
}

// ------------- bf16 GEMM1 v3 (r4-PASSED, verbatim): single-buffer 32KB + T2 swizzle -------------
__global__ __launch_bounds__(256)
void k_gemm1n(const void* __restrict__ enc,
              const ushort_t* __restrict__ enc_bf,
              const ushort_t* __restrict__ Wenc_bf,
              const float* __restrict__ proj_dec,
              const void* __restrict__ cov,
              const void* __restrict__ Wcov,
              const int* __restrict__ flagp,
              ushort_t* __restrict__ feats) {
    __shared__ ushort_t As[BM * BK2];   // 16 KB
    __shared__ ushort_t Bs[BN * BK2];   // 16 KB
    const int f32 = *flagp;
    const ushort_t* Abf = f32 ? enc_bf : (const ushort_t*)enc;

    const int lid = ((blockIdx.x & 7) << 8) | (blockIdx.x >> 3);
    const int m0 = (lid >> 2) * BM;
    const int n0 = (lid & 3) * BN;

    const int tid = threadIdx.x;
    const int lane = tid & 63, wave = tid >> 6;
    const int quad = lane >> 4, l16 = lane & 15;
    const int wm = wave >> 1, wn = wave & 1;
    const int l8r = lane >> 3;                       // row within 8-row chunk (0..7)
    const int l8c = ((lane & 7) ^ l8r) * 8;          // pre-swizzled source column

    float4_t acc[4][4];
    #pragma unroll
    for (int i = 0; i < 4; i++)
        #pragma unroll
        for (int j = 0; j < 4; j++) acc[i][j] = (float4_t){0.f, 0.f, 0.f, 0.f};

    #pragma unroll
    for (int kt = 0; kt < NT; kt++) {
        __syncthreads();                     // prior iter's reads done before overwrite
        #pragma unroll
        for (int i = 0; i < 4; i++) {
            int ch = i * 4 + wave;           // 16 chunks of 8 rows x 64 cols (1 KB each)
            glds16(Abf     + (((size_t)(m0 + ch * 8 + l8r)) << 9) + kt * BK2 + l8c, &As[ch * 512]);
            glds16(Wenc_bf + (((size_t)(n0 + ch * 8 + l8r)) << 9) + kt * BK2 + l8c, &Bs[ch * 512]);
        }
        __syncthreads();                     // compiler drains vmcnt before barrier
        #pragma unroll
        for (int kk = 0; kk < 2; kk++) {
            short8 af[4], bfv[4];
            #pragma unroll
            for (int mt = 0; mt < 4; mt++) {
                int row = wm * 64 + mt * 16 + l16;
                int col = (kk * 32 + quad * 8) ^ ((row & 7) << 3);
                af[mt] = *(const short8*)&As[row * BK2 + col];
            }
            #pragma unroll
            for (int nt = 0; nt < 4; nt++) {
                int row = wn * 64 + nt * 16 + l16;
                int col = (kk * 32 + quad * 8) ^ ((row & 7) << 3);
                bfv[nt] = *(const short8*)&Bs[row * BK2 + col];
            }
            #pragma unroll
            for (int mt = 0; mt < 4; mt++)
                #pragma unroll
                for (int nt = 0; nt < 4; nt++)
                    acc[mt][nt] = __builtin_amdgcn_mfma_f32_16x16x32_bf16(af[mt], bfv[nt], acc[mt][nt], 0, 0, 0);
        }
    }

    // ---- epilogue: bounce the 128x128 bf16 tile through the (now-dead) LDS ----
    __syncthreads();   // all LDS reads of the K-loop done before reuse
    ushort_t* myhalf = wm ? Bs : As;
    #pragma unroll
    for (int mt = 0; mt < 4; mt++) {
        #pragma unroll
        for (int r = 0; r < 4; r++) {
            int lr = mt * 16 + quad * 4 + r;         // row within this wave's half (0..63)
            int grow = wm * 64 + lr;                 // row within the 128-tile
            int m = m0 + grow;
            int b = m >> 10;
            float covv = ldmix(f32, cov, m);
            #pragma unroll
            for (int nt = 0; nt < 4; nt++) {
                int lc = wn * 64 + nt * 16 + l16;    // col within the 128-tile
                int n = n0 + lc;
                float v = acc[mt][nt][r] + proj_dec[b * AA + n] + covv * ldmix(f32, Wcov, n);
                myhalf[lr * 128 + (lc ^ ((grow & 7) << 3))] = f2bf(fast_tanh(v));
            }
        }
    }
    __syncthreads();
    #pragma unroll
    for (int rep = 0; rep < 8; rep++) {
        int row = rep * 16 + (tid >> 4);             // 0..127, each exactly once
        int c8 = (tid & 15) * 8;                     // 8-aligned col chunk
        const ushort_t* half = (row < 64) ? As : Bs;
        short8 vv = *(const short8*)&half[(row & 63) * 128 + (c8 ^ ((row & 7) << 3))];
        *(short8*)&feats[(size_t)(m0 + row) * AA + n0 + c8] = vv;
    }
}

// ------------- bf16 GEMM2 v3 (r4-PASSED, verbatim): same single-buffer structure -------------
__global__ __launch_bounds__(256)
void k_gemm2n(const ushort_t* __restrict__ Xg,      // feats (bf16)
              const ushort_t* __restrict__ W1_bf,
              const void* __restrict__ b1,
              const void* __restrict__ wattn,
              const int* __restrict__ flagp,
              float* __restrict__ scores) {
    __shared__ ushort_t As[BM * BK2];
    __shared__ ushort_t Bs[BN * BK2];
    const int f32 = *flagp;

    const int lid = ((blockIdx.x & 7) << 8) | (blockIdx.x >> 3);
    const int m0 = (lid >> 2) * BM;
    const int n0 = (lid & 3) * BN;

    const int tid = threadIdx.x;
    const int lane = tid & 63, wave = tid >> 6;
    const int quad = lane >> 4, l16 = lane & 15;
    const int wm = wave >> 1, wn = wave & 1;
    const int l8r = lane >> 3;
    const int l8c = ((lane & 7) ^ l8r) * 8;

    float4_t acc[4][4];
    #pragma unroll
    for (int i = 0; i < 4; i++)
        #pragma unroll
        for (int j = 0; j < 4; j++) acc[i][j] = (float4_t){0.f, 0.f, 0.f, 0.f};

    #pragma unroll
    for (int kt = 0; kt < NT; kt++) {
        __syncthreads();
        #pragma unroll
        for (int i = 0; i < 4; i++) {
            int ch = i * 4 + wave;
            glds16(Xg    + (((size_t)(m0 + ch * 8 + l8r)) << 9) + kt * BK2 + l8c, &As[ch * 512]);
            glds16(W1_bf + (((size_t)(n0 + ch * 8 + l8r)) << 9) + kt * BK2 + l8c, &Bs[ch * 512]);
        }
        __syncthreads();
        #pragma unroll
        for (int kk = 0; kk < 2; kk++) {
            short8 af[4], bfv[4];
            #pragma unroll
            for (int mt = 0; mt < 4; mt++) {
                int row = wm * 64 + mt * 16 + l16;
                int col = (kk * 32 + quad * 8) ^ ((row & 7) << 3);
                af[mt] = *(const short8*)&As[row * BK2 + col];
            }
            #pragma unroll
            for (int nt = 0; nt < 4; nt++) {
                int row = wn * 64 + nt * 16 + l16;
                int col = (kk * 32 + quad * 8) ^ ((row & 7) << 3);
                bfv[nt] = *(const short8*)&Bs[row * BK2 + col];
            }
            #pragma unroll
            for (int mt = 0; mt < 4; mt++)
                #pragma unroll
                for (int nt = 0; nt < 4; nt++)
                    acc[mt][nt] = __builtin_amdgcn_mfma_f32_16x16x32_bf16(af[mt], bfv[nt], acc[mt][nt], 0, 0, 0);
        }
    }

    float wv[4], bv[4];
    #pragma unroll
    for (int nt = 0; nt < 4; nt++) {
        int n = n0 + wn * 64 + nt * 16 + l16;
        wv[nt] = ldmix(f32, wattn, n);
        bv[nt] = ldmix(f32, b1, n);
    }
    #pragma unroll
    for (int mt = 0; mt < 4; mt++) {
        #pragma unroll
        for (int r = 0; r < 4; r++) {
            int m = m0 + wm * 64 + mt * 16 + quad * 4 + r;
            float s = 0.f;
            #pragma unroll
            for (int nt = 0; nt < 4; nt++) {
                int n = n0 + wn * 64 + nt * 16 + l16;
                float v = acc[mt][nt][r] + bv[nt] + bf2f(Xg[(size_t)m * AA + n]);
                s += fast_tanh(v) * wv[nt];
            }
            s += __shfl_xor(s, 1);
            s += __shfl_xor(s, 2);
            s += __shfl_xor(s, 4);
            s += __shfl_xor(s, 8);
            if (l16 == 0) atomicAdd(&scores[m], s);
        }
    }
}

__global__ void k_softmax(const float* __restrict__ scores,
                          const int* __restrict__ mask,
                          const void* __restrict__ cov,
                          const int* __restrict__ flagp,
                          float* __restrict__ attnw,
                          void* __restrict__ dout) {
    __shared__ float red[4];
    const int f32 = *flagp;
    int b = blockIdx.x, tid = threadIdx.x;
    float v[4];
    #pragma unroll
    for (int i = 0; i < 4; i++) {
        int s = tid + i * 256;
        float sc = scores[b * SS + s];
        if (mask[b * SS + s] == 0) sc = -1e9f;
        v[i] = sc;
    }
    float mx = fmaxf(fmaxf(v[0], v[1]), fmaxf(v[2], v[3]));
    #pragma unroll
    for (int off = 1; off < 64; off <<= 1) mx = fmaxf(mx, __shfl_xor(mx, off));
    if ((tid & 63) == 0) red[tid >> 6] = mx;
    __syncthreads();
    mx = fmaxf(fmaxf(red[0], red[1]), fmaxf(red[2], red[3]));
    __syncthreads();
    float e[4], sum = 0.f;
    #pragma unroll
    for (int i = 0; i < 4; i++) { e[i] = expf(v[i] - mx); sum += e[i]; }
    #pragma unroll
    for (int off = 1; off < 64; off <<= 1) sum += __shfl_xor(sum, off);
    if ((tid & 63) == 0) red[tid >> 6] = sum;
    __syncthreads();
    sum = red[0] + red[1] + red[2] + red[3];
    float inv = 1.0f / sum;
    #pragma unroll
    for (int i = 0; i < 4; i++) {
        int s = tid + i * 256;
        float w = e[i] * inv;
        attnw[b * SS + s] = w;
        stmix(f32, dout, 32768L + (long)b * SS + s, w);
        stmix(f32, dout, 98304L + (long)b * SS + s, ldmix(f32, cov, (long)b * SS + s) + w);
    }
}

// ---- context with per-(b,sc) partials, no atomics (pre path; data always bf16) ----
__global__ void k_context_p(const void* __restrict__ enc,
                            const ushort_t* __restrict__ enc_bf,
                            const float* __restrict__ attnw,
                            const int* __restrict__ flagp,
                            float2_t* __restrict__ ctxp) {
    const int f32 = *flagp;
    const unsigned int* base = (const unsigned int*)(f32 ? (const void*)enc_bf : enc);
    int b = blockIdx.x, sc = blockIdx.y;
    int tid = threadIdx.x;
    base += ((size_t)b * SS + sc * 128) * (EE / 2);
    float a0 = 0.f, a1 = 0.f;
    const float* wrow = attnw + b * SS + sc * 128;
    for (int s = 0; s < 128; s++) {
        float w = wrow[s];
        unsigned int u = base[(size_t)s * (EE / 2) + tid];
        a0 += w * bf2f((ushort_t)(u & 0xffff));
        a1 += w * bf2f((ushort_t)(u >> 16));
    }
    ctxp[((b << 3) + sc) * 256 + tid] = (float2_t){a0, a1};
}

// legacy context (fallback path): atomics into ctx
__global__ void k_context(const void* __restrict__ enc,
                          const ushort_t* __restrict__ enc_bf,
                          const int pre,
                          const float* __restrict__ attnw,
                          const int* __restrict__ flagp,
                          float* __restrict__ ctx) {
    int f32 = *flagp;
    const void* e = enc;
    if (pre && f32) { e = enc_bf; f32 = 0; }
    int b = blockIdx.x, sc = blockIdx.y;
    int tid = threadIdx.x;
    float a0 = 0.f, a1 = 0.f;
    const float* wrow = attnw + b * SS + sc * 128;
    if (f32) {
        const float* base = (const float*)e + ((size_t)b * SS + sc * 128) * EE;
        for (int s = 0; s < 128; s++) {
            float w = wrow[s];
            float2_t u = *(const float2_t*)(base + (size_t)s * EE + 2 * tid);
            a0 += w * u[0];
            a1 += w * u[1];
        }
    } else {
        const unsigned int* base = (const unsigned int*)e + ((size_t)b * SS + sc * 128) * (EE / 2);
        for (int s = 0; s < 128; s++) {
            float w = wrow[s];
            unsigned int u = base[(size_t)s * (EE / 2) + tid];
            a0 += w * bf2f((ushort_t)(u & 0xffff));
            a1 += w * bf2f((ushort_t)(u >> 16));
        }
    }
    atomicAdd(&ctx[b * EE + 2 * tid], a0);
    atomicAdd(&ctx[b * EE + 2 * tid + 1], a1);
}

// ---- gate with partial reduce (pre path) ----
__global__ __launch_bounds__(256)
void k_gate_p(const float2_t* __restrict__ ctxp,
              const void* __restrict__ dec,
              const void* __restrict__ Wg,
              const void* __restrict__ bg,
              const int* __restrict__ flagp,
              void* __restrict__ dout) {
    __shared__ float gin[EE + DD];
    const int f32 = *flagp;
    const int b = blockIdx.y;
    const int tid = threadIdx.x, lane = tid & 63, wave = tid >> 6;
    float c0 = 0.f, c1 = 0.f;
    #pragma unroll
    for (int sc = 0; sc < 8; sc++) {
        float2_t v = ctxp[((b << 3) + sc) * 256 + tid];
        c0 += v[0]; c1 += v[1];
    }
    gin[2 * tid] = c0;
    gin[2 * tid + 1] = c1;
    gin[EE + tid]       = ldmix(f32, dec, (long)b * DD + tid);
    gin[EE + tid + 256] = ldmix(f32, dec, (long)b * DD + tid + 256);
    __syncthreads();
    const int a = blockIdx.x * 4 + wave;
    float s = 0.f;
    if (f32) {
        const float* wr = (const float*)Wg + (size_t)a * (EE + DD) + lane * 16;
        #pragma unroll
        for (int j = 0; j < 16; j++) s += wr[j] * gin[lane * 16 + j];
    } else {
        const ushort_t* wr = (const ushort_t*)Wg + (size_t)a * (EE + DD) + lane * 16;
        short8 w0 = *(const short8*)wr;
        short8 w1 = *(const short8*)(wr + 8);
        #pragma unroll
        for (int j = 0; j < 8; j++) {
            s += bf2f((ushort_t)w0[j]) * gin[lane * 16 + j];
            s += bf2f((ushort_t)w1[j]) * gin[lane * 16 + 8 + j];
        }
    }
    #pragma unroll
    for (int off = 1; off < 64; off <<= 1) s += __shfl_xor(s, off);
    if (lane == 0) {
        float acc = s + ldmix(f32, bg, a);
        float g = 1.f / (1.f + __expf(-acc));
        stmix(f32, dout, (long)b * AA + a, g * gin[a]);
    }
}

// legacy gate (fallback path)
__global__ __launch_bounds__(256)
void k_gate(const float* __restrict__ ctx,
            const void* __restrict__ dec,
            const void* __restrict__ Wg,
            const void* __restrict__ bg,
            const int* __restrict__ flagp,
            void* __restrict__ dout) {
    __shared__ float gin[EE + DD];
    const int f32 = *flagp;
    const int b = blockIdx.y;
    const int tid = threadIdx.x, lane = tid & 63, wave = tid >> 6;
    gin[2 * tid]     = ctx[b * EE + 2 * tid];
    gin[2 * tid + 1] = ctx[b * EE + 2 * tid + 1];
    gin[EE + tid]       = ldmix(f32, dec, (long)b * DD + tid);
    gin[EE + tid + 256] = ldmix(f32, dec, (long)b * DD + tid + 256);
    __syncthreads();
    const int a = blockIdx.x * 4 + wave;
    float s = 0.f;
    if (f32) {
        const float* wr = (const float*)Wg + (size_t)a * (EE + DD) + lane * 16;
        #pragma unroll
        for (int j = 0; j < 16; j++) s += wr[j] * gin[lane * 16 + j];
    } else {
        const ushort_t* wr = (const ushort_t*)Wg + (size_t)a * (EE + DD) + lane * 16;
        short8 w0 = *(const short8*)wr;
        short8 w1 = *(const short8*)(wr + 8);
        #pragma unroll
        for (int j = 0; j < 8; j++) {
            s += bf2f((ushort_t)w0[j]) * gin[lane * 16 + j];
            s += bf2f((ushort_t)w1[j]) * gin[lane * 16 + 8 + j];
        }
    }
    #pragma unroll
    for (int off = 1; off < 64; off <<= 1) s += __shfl_xor(s, off);
    if (lane == 0) {
        float acc = s + ldmix(f32, bg, a);
        float g = 1.f / (1.f + __expf(-acc));
        stmix(f32, dout, (long)b * AA + a, g * ctx[b * EE + a]);
    }
}

extern "C" void kernel_launch(void* const* d_in, const int* in_sizes, int n_in,
                              void* d_out, int out_size, void* d_ws, size_t ws_size,
                              hipStream_t stream) {
    const void* enc   = d_in[0];
    const void* dec   = d_in[1];
    const int*  mask  = (const int*)d_in[2];
    const void* cov   = d_in[3];
    const void* Wenc  = d_in[4];
    const void* Wdec  = d_in[5];
    const void* wattn = d_in[6];
    const void* Wl1   = d_in[7];
    const void* b1    = d_in[8];
    const void* Wcov  = d_in[9];
    const void* Wg    = d_in[10];
    const void* bg    = d_in[11];

    char* ws = (char*)d_ws;
    float*    scores = (float*)ws;                  // 262144 B
    float*    ctx    = (float*)(ws + 262144);       // 131072 B (legacy path only)
    float*    attnw  = (float*)(ws + 393216);       // 262144 B
    float*    projd  = (float*)(ws + 655360);       // 131072 B
    int*      flag   = (int*)(ws + 786432);         // 4 B
    ushort_t* feats  = (ushort_t*)(ws + 1048576);   // 67108864 B -> 68157440
    ushort_t* W1b    = (ushort_t*)(ws + 68157440);  // 524288 B   -> 68681728
    ushort_t* Wencb  = (ushort_t*)(ws + 68681728);  // 524288 B   -> 69206016
    ushort_t* encb   = (ushort_t*)(ws + 69206016);  // 67108864 B -> 136314880
    float2_t* ctxp   = (float2_t*)(ws + 136314880); // 1048576 B  -> 137363456
    const int pre2 = (ws_size >= 69206016UL)  ? 1 : 0;  // bf16 weight copies fit
    const int pre1 = (ws_size >= 136314880UL) ? 1 : 0;  // bf16 enc copy fits
    const int pre3 = (ws_size >= 137363456UL) ? 1 : 0;  // ctx partials also fit

    hipMemsetAsync(ws, 0, 393216, stream);
    k_detect<<<1, 256, 0, stream>>>((const ushort_t*)enc, flag);
    if (pre2)
        k_conv_w<<<dim3(128, 2), 256, 0, stream>>>(Wenc, Wl1, flag, Wencb, W1b);
    if (pre1)
        k_conv_enc<<<4096, 256, 0, stream>>>(enc, flag, encb);
    k_proj_dec<<<dim3(AA / 4, BB), 256, 0, stream>>>(dec, Wdec, flag, projd);
    if (pre1)
        k_gemm1n<<<2048, 256, 0, stream>>>(enc, encb, Wencb, projd, cov, Wcov, flag, feats);
    else
        k_gemm1<<<dim3(AA / BN, MM / BM), 256, 0, stream>>>(enc, Wenc, projd, cov, Wcov, flag, feats);
    if (pre2)
        k_gemm2n<<<2048, 256, 0, stream>>>(feats, W1b, b1, wattn, flag, scores);
    else
        k_gemm2<<<dim3(AA / BN, MM / BM), 256, 0, stream>>>(feats, Wl1, b1, wattn, flag, scores);
    k_softmax<<<BB, 256, 0, stream>>>(scores, mask, cov, flag, attnw, d_out);
    if (pre1 && pre3) {
        k_context_p<<<dim3(BB, 8), 256, 0, stream>>>(enc, encb, attnw, flag, ctxp);
        k_gate_p<<<dim3(AA / 4, BB), 256, 0, stream>>>(ctxp, dec, Wg, bg, flag, d_out);
    } else {
        k_context<<<dim3(BB, 8), 256, 0, stream>>>(enc, encb, pre1, attnw, flag, ctx);
        k_gate<<<dim3(AA / 4, BB), 256, 0, stream>>>(ctx, dec, Wg, bg, flag, d_out);
    }
}